// Round 8
// baseline (204.935 us; speedup 1.0000x reference)
//
#include <hip/hip_runtime.h>

#define BN_INV  0.99999500003749981f
#define QSCALE  0.21320071635561041f   // 22^-0.5

typedef unsigned int uint;
typedef unsigned short u16;
typedef __attribute__((ext_vector_type(8))) short s16x8;
typedef __attribute__((ext_vector_type(4))) float f32x4;

// ---- ws layout ----
// float offsets:
#define OFF_BCAT 0         // 264
#define OFF_V    512       // 8192*88 fp32 (qkv out, dwt in)
#define OFF_MP   721408    // 8192*88 fp32 (final residual)   ends 1442304 fl
// short offsets (shorts region starts at 2884608 sh):
#define SW0    2884608
#define SB1    (SW0)            // 320 x 96
#define SB2B   (SW0+30720)      // 128 x 288
#define SB3B   (SW0+67584)      // 128 x 288
#define SB3C   (SW0+104448)     // 128 x 480
#define SBMP   (SW0+165888)     // 128 x 288
#define SBQKV  (SW0+202752)     // 384 x 96
#define SBOUT  (SW0+239616)     // 128 x 192  ends SW0+264192
#define SXB    3148800     // xb   [8192][88]  dead after conv1
#define SXCAT  3869696     // XCAT [8192][264] dead after mp
#define SX2    6032384     // X2   [8192][88]  dead after mp
#define ST3B   6753280     // T3B  [8192][88]  dead after conv5
#define SX3    7474176     // X3   [8192][88]  dead after mp
#define SMPB   8195072     // MPb  [8192][88]  dead after qkv  ends 8915968
// overlays (written after their hosts die):
#define SQB    3869696     // Qb  [16][2048][32]  (over XCAT)
#define SKB    4918272     // Kb  [16][2048][32]  (over XCAT)
#define SCDT   5966848     // CDT [16][16][2048]  (over XCAT tail + X2)
#define SXOB   6753280     // XOb [8192][112]     (over T3B + X3 head)

__constant__ float c_dlo[8] = {-0.010597401784997278f, 0.032883011666982945f,
    0.030841381835986965f, -0.18703481171888114f, -0.02798376941698385f,
    0.6308807679295904f, 0.7148465705525415f, 0.23037781330885523f};
__constant__ float c_dhi[8] = {-0.23037781330885523f, 0.7148465705525415f,
    -0.6308807679295904f, -0.02798376941698385f, 0.18703481171888114f,
    0.030841381835986965f, -0.032883011666982945f, -0.010597401784997278f};

__device__ __forceinline__ u16 f2bf(float f) {
    uint u = __float_as_uint(f);
    uint r = u + 0x7fffu + ((u >> 16) & 1u);
    return (u16)(r >> 16);
}

// ---------------- weight prep + x->bf16 ----------------------------------
__global__ __launch_bounds__(256) void prepk(
    const float* __restrict__ x,
    const float* __restrict__ w1, const float* __restrict__ w2a, const float* __restrict__ w2b,
    const float* __restrict__ w3a, const float* __restrict__ w3b, const float* __restrict__ w3c,
    const float* __restrict__ g1, const float* __restrict__ g2a, const float* __restrict__ g2b,
    const float* __restrict__ g3a, const float* __restrict__ g3b, const float* __restrict__ g3c,
    const float* __restrict__ b1, const float* __restrict__ b2a, const float* __restrict__ b3a,
    const float* __restrict__ Wmp, const float* __restrict__ Wq, const float* __restrict__ Wk,
    const float* __restrict__ Wv, const float* __restrict__ Wout, float* __restrict__ ws)
{
    u16* wu = (u16*)ws;
    int r = blockIdx.x * 256 + threadIdx.x;
    if (r < 264) {
        ws[OFF_BCAT + r] = (r < 88) ? b1[r] : (r < 176 ? b2a[r-88] : b3a[r-176]);
        return;
    }
    r -= 264;
    if (r < 320*96) {                       // WB1: cat(w1,w2a,w3a) folded
        int n = r / 96, kk = r % 96; float v = 0.f;
        if (kk < 88 && n < 264) {
            if (n < 88)       v = w1 [n*88+kk]       * g1 [n];
            else if (n < 176) v = w2a[(n-88)*88+kk]  * g2a[n-88];
            else              v = w3a[(n-176)*88+kk] * g3a[n-176];
            v *= BN_INV;
        }
        wu[SB1 + r] = f2bf(v); return;
    }
    r -= 320*96;
    if (r < 128*288) {                      // WB2B
        int n = r / 288, kk = r % 288, t = kk/96, i = kk%96; float v = 0.f;
        if (n < 88 && i < 88) v = w2b[n*264 + i*3 + t] * g2b[n] * BN_INV;
        wu[SB2B + r] = f2bf(v); return;
    }
    r -= 128*288;
    if (r < 128*288) {                      // WB3B
        int n = r / 288, kk = r % 288, t = kk/96, i = kk%96; float v = 0.f;
        if (n < 88 && i < 88) v = w3b[n*264 + i*3 + t] * g3b[n] * BN_INV;
        wu[SB3B + r] = f2bf(v); return;
    }
    r -= 128*288;
    if (r < 128*480) {                      // WB3C
        int n = r / 480, kk = r % 480, t = kk/96, i = kk%96; float v = 0.f;
        if (n < 88 && i < 88) v = w3c[n*440 + i*5 + t] * g3c[n] * BN_INV;
        wu[SB3C + r] = f2bf(v); return;
    }
    r -= 128*480;
    if (r < 128*288) {                      // WBMP
        int n = r / 288, kk = r % 288, c = kk/96, i = kk%96; float v = 0.f;
        if (n < 88 && i < 88) v = Wmp[n*264 + c*88 + i];
        wu[SBMP + r] = f2bf(v); return;
    }
    r -= 128*288;
    if (r < 384*96) {                       // WBQKV (q-scale folded)
        int n = r / 96, kk = r % 96, sec = n / 128, o = n % 128; float v = 0.f;
        if (o < 88 && kk < 88) {
            if (sec == 0)      v = Wq[o*88+kk] * QSCALE;
            else if (sec == 1) v = Wk[o*88+kk];
            else               v = Wv[o*88+kk];
        }
        wu[SBQKV + r] = f2bf(v); return;
    }
    r -= 384*96;
    if (r < 128*192) {                      // WBOUT
        int n = r / 192, kk = r % 192; float v = 0.f;
        if (n < 88 && kk < 112) v = Wout[n*112 + kk];
        wu[SBOUT + r] = f2bf(v); return;
    }
    r -= 128*192;
    if (r < 8192*88) {                      // xb
        wu[SXB + r] = f2bf(x[r]); return;
    }
}

// ---------------- generic bf16 MFMA GEMM, 64x64 tile, K-chunks of 96 ------
struct GemmChunks {
    int soff[5];    // short offset of bf16 source base
    int stride[5];  // in shorts
    int shift[5];   // row shift (halo)
    int cols[5];    // valid cols
};

// MODE 0: normal; MODE 1: qkv scatter (+Q/K pad zero); MODE 2: dual conv3
// OUTM bit0: write bf16 outb; bit1: write fp32 outf
template<int NCH, int MODE, int OUTM>
__global__ __launch_bounds__(256) void gemmk(GemmChunks ch,
    const u16* __restrict__ wsrc,
    const u16* __restrict__ Bw, const u16* __restrict__ Bw2, int Ktot,
    const float* __restrict__ bias, const float* __restrict__ bias2,
    const float* __restrict__ resid, int relu,
    u16* __restrict__ outb, u16* __restrict__ outb2,
    float* __restrict__ outf, int outStride, int N)
{
    __shared__ u16 As[64*104];
    __shared__ u16 Bs[64*104];
    int tid = threadIdx.x;
    int lane = tid & 63, w = tid >> 6, wr = w >> 1, wc = w & 1;
    int p0 = blockIdx.x * 64;
    int nb = blockIdx.y;
    int which = (MODE == 2) ? (nb >> 1) : 0;
    int nbl   = (MODE == 2) ? (nb & 1) : nb;
    const u16* Bw_ = (MODE == 2 && which) ? Bw2 : Bw;
    int bs = p0 & ~2047, be = bs + 2048;

    f32x4 acc[2][2];
    #pragma unroll
    for (int a = 0; a < 2; a++)
        #pragma unroll
        for (int b = 0; b < 2; b++) acc[a][b] = (f32x4){0.f,0.f,0.f,0.f};

    int ar0 = (wr*32 + (lane&15))*104 + (lane>>4)*8;
    int br0 = (wc*32 + (lane&15))*104 + (lane>>4)*8;

    int4 ra[3], rb[3];
    auto loadC = [&](int c) {
        int soff = ch.soff[c] + which*88;
        int stride = ch.stride[c], shift = ch.shift[c], cols = ch.cols[c];
        #pragma unroll
        for (int t = 0; t < 3; t++) {
            int e = tid + t*256;
            int r = e / 12, seg = e % 12;
            int row = p0 + r + shift;
            int4 v = {0,0,0,0};
            if (row >= bs && row < be && seg*8 < cols)
                v = *(const int4*)&wsrc[(size_t)soff + (size_t)row*stride + seg*8];
            ra[t] = v;
            rb[t] = *(const int4*)&Bw_[((size_t)(nbl*64 + r))*Ktot + c*96 + seg*8];
        }
    };

    loadC(0);
    for (int c = 0; c < NCH; c++) {
        #pragma unroll
        for (int t = 0; t < 3; t++) {
            int e = tid + t*256;
            int r = e / 12, seg = e % 12;
            *(int4*)&As[r*104 + seg*8] = ra[t];
            *(int4*)&Bs[r*104 + seg*8] = rb[t];
        }
        __syncthreads();
        if (c + 1 < NCH) loadC(c + 1);      // prefetch flies under MFMA
        #pragma unroll
        for (int ks = 0; ks < 3; ks++) {
            s16x8 a0 = *(const s16x8*)&As[ar0 + ks*32];
            s16x8 a1 = *(const s16x8*)&As[ar0 + 16*104 + ks*32];
            s16x8 b0 = *(const s16x8*)&Bs[br0 + ks*32];
            s16x8 b1 = *(const s16x8*)&Bs[br0 + 16*104 + ks*32];
            acc[0][0] = __builtin_amdgcn_mfma_f32_16x16x32_bf16(a0, b0, acc[0][0], 0, 0, 0);
            acc[0][1] = __builtin_amdgcn_mfma_f32_16x16x32_bf16(a0, b1, acc[0][1], 0, 0, 0);
            acc[1][0] = __builtin_amdgcn_mfma_f32_16x16x32_bf16(a1, b0, acc[1][0], 0, 0, 0);
            acc[1][1] = __builtin_amdgcn_mfma_f32_16x16x32_bf16(a1, b1, acc[1][1], 0, 0, 0);
        }
        __syncthreads();
    }

    int rbase = p0 + wr*32 + (lane>>4)*4;
    if (MODE != 1) {
        u16* outb_ = (MODE == 2 && which) ? outb2 : outb;
        const float* bias_ = (MODE == 2 && which) ? bias2 : bias;
        int cbase = nbl*64 + wc*32 + (lane&15);
        #pragma unroll
        for (int fn = 0; fn < 2; fn++) {
            int col = cbase + fn*16;
            if (col < N) {
                float bb = bias_ ? bias_[col] : 0.f;
                #pragma unroll
                for (int fm = 0; fm < 2; fm++)
                    #pragma unroll
                    for (int j = 0; j < 4; j++) {
                        int row = rbase + fm*16 + j;
                        float v = acc[fm][fn][j] + bb;
                        if (relu) v = fmaxf(v, 0.f);
                        if (resid) v += resid[(size_t)row*outStride + col];
                        if (OUTM & 1) outb_[(size_t)row*outStride + col] = f2bf(v);
                        if (OUTM & 2) outf[(size_t)row*outStride + col] = v;
                    }
            }
        }
    } else {
        u16* wq = outb;    // wu base
        int sec = nb >> 1;
        #pragma unroll
        for (int fn = 0; fn < 2; fn++) {
            int cw = (nb&1)*64 + wc*32 + fn*16 + (lane&15);
            if (cw < 88) {
                int h = cw / 22, d = cw % 22;
                #pragma unroll
                for (int fm = 0; fm < 2; fm++)
                    #pragma unroll
                    for (int j = 0; j < 4; j++) {
                        int row = rbase + fm*16 + j;
                        int b = row >> 11, s = row & 2047;
                        float v = acc[fm][fn][j];
                        if (sec == 0)
                            wq[SQB + ((size_t)(b*4+h)*2048 + s)*32 + d] = f2bf(v);
                        else if (sec == 1)
                            wq[SKB + ((size_t)(b*4+h)*2048 + s)*32 + d] = f2bf(v);
                        else
                            outf[OFF_V + (size_t)row*88 + cw] = v;
                    }
            } else if (sec < 2 && cw < 128) {
                // idle cols zero the Q/K pads d=22..31 (40 slots = 4h x 10d)
                int t = cw - 88, h = t / 10, dpad = 22 + t % 10;
                size_t sqk = (sec == 0) ? (size_t)SQB : (size_t)SKB;
                #pragma unroll
                for (int fm = 0; fm < 2; fm++)
                    #pragma unroll
                    for (int j = 0; j < 4; j++) {
                        int row = rbase + fm*16 + j;
                        int b = row >> 11, s = row & 2047;
                        wq[sqk + ((size_t)(b*4+h)*2048 + s)*32 + dpad] = 0;
                    }
            }
        }
    }
}

// ---------------- DWT(V) -> CDT bf16 + cA scatter (s-fast, coalesced) -----
__global__ __launch_bounds__(256) void dwtk(float* __restrict__ ws)
{
    u16* wu = (u16*)ws;
    __shared__ float vs[32*89];             // 32 pos x 88, pad 89 (bank-clean)
    int tid = threadIdx.x;
    int p0 = blockIdx.x * 32;
    const float* V = ws + OFF_V;
    for (int e = tid; e < 32*88; e += 256) {
        int p = e / 88, c = e - p*88;
        vs[p*89 + c] = V[(size_t)p0*88 + e];
    }
    __syncthreads();
    int b = p0 >> 11, sbase = p0 & 2047;
    #pragma unroll
    for (int it = 0; it < 7; it++) {
        int idx = it*256 + tid;             // 1792 = 32 pos x 56 (h,jj)
        int p = idx & 31, hjj = idx >> 5;
        int h = hjj / 14, jj = hjj - h*14;
        const float* v = &vs[p*89 + h*22];
        float ca = 0.f, cd = 0.f;
        #pragma unroll
        for (int t = 0; t < 8; t++) {
            int pp = 1 + 2*jj + t;
            int oi = pp < 7 ? 6 - pp : (pp < 29 ? pp - 7 : 50 - pp);
            float vv = v[oi];
            ca = fmaf(vv, c_dlo[7-t], ca);
            cd = fmaf(vv, c_dhi[7-t], cd);
        }
        int s = sbase + p;
        wu[SCDT + ((size_t)((b*4+h)*16 + jj))*2048 + s] = f2bf(cd);   // s-fast: 64B runs
        int hs = h*2048 + s, s2 = hs >> 2, qd = hs & 3;
        wu[SXOB + ((size_t)b*2048 + s2)*112 + 56 + qd*14 + jj] = f2bf(ca);
    }
    {   // CDT pad rows d=14,15 (256 writes, s-fast)
        int p = tid & 31, t = tid >> 5;
        int h = t >> 1, dd = 14 + (t & 1);
        wu[SCDT + ((size_t)((b*4+h)*16 + dd))*2048 + sbase + p] = 0;
    }
}

// ---------------- MFMA flash attention, 4-way split-K + defer-max ---------
// 512 thr = 8 waves; grid (64 q-tiles of 32, 16 bh). Wave w: q-sub (w&1),
// key-quarter (w>>1) of 512 keys in 8 tiles of 64. Partials merged in LDS.
__global__ __launch_bounds__(512, 4) void attnk(float* __restrict__ ws)
{
    const u16* wu = (const u16*)ws;
    u16* wua = (u16*)ws;
    __shared__ __align__(16) u16 Kt[4*64*40];      // [quar][key64][40]
    __shared__ __align__(16) u16 CDt[4*16*72];     // [quar][d16][72]
    __shared__ __align__(16) u16 Pb[8][16*72];     // per-wave P
    __shared__ float cb[8][16];
    int tid = threadIdx.x, lane = tid & 63, w = tid >> 6;
    int bh = blockIdx.y;
    int qsub = w & 1, quar = w >> 1;
    int q0 = blockIdx.x * 32 + qsub * 16;
    int qrow = lane & 15, grp = lane >> 4;

    s16x8 qf = *(const s16x8*)&wu[SQB + ((size_t)bh*2048 + q0 + qrow)*32 + grp*8];
    const u16* Kbase = wu + SKB + (size_t)bh*2048*32;
    const u16* Cbase = wu + SCDT + (size_t)bh*16*2048;
    const u16* Kh = &Kt[quar*2560];
    const u16* Ch = &CDt[quar*1152];

    f32x4 o = (f32x4){0.f,0.f,0.f,0.f};
    float m = -1e30f, l = 0.f;

    for (int kt = 0; kt < 8; kt++) {
        __syncthreads();
        #pragma unroll
        for (int t = 0; t < 2; t++) {      // K: 4 quarters x 64 keys, 1024 int4
            int e = tid + t*512;
            int qq = e >> 8, rr = (e >> 2) & 63, seg = e & 3;
            *(int4*)&Kt[qq*2560 + rr*40 + seg*8] =
                *(const int4*)&Kbase[(size_t)(qq*512 + kt*64 + rr)*32 + seg*8];
        }
        {   // cD^T: 4 quarters x 16 d x 64 keys, 512 int4
            int qq = tid >> 7, d = (tid >> 3) & 15, seg = tid & 7;
            *(int4*)&CDt[qq*1152 + d*72 + seg*8] =
                *(const int4*)&Cbase[(size_t)d*2048 + qq*512 + kt*64 + seg*8];
        }
        __syncthreads();

        f32x4 s4[4];
        #pragma unroll
        for (int sub = 0; sub < 4; sub++) {
            s16x8 kf = *(const s16x8*)&Kh[(sub*16 + qrow)*40 + grp*8];
            s4[sub] = __builtin_amdgcn_mfma_f32_16x16x32_bf16(kf, qf,
                        (f32x4){0.f,0.f,0.f,0.f}, 0, 0, 0);
        }
        float sv[16];
        #pragma unroll
        for (int sub = 0; sub < 4; sub++)
            #pragma unroll
            for (int j = 0; j < 4; j++) sv[sub*4+j] = s4[sub][j];

        float mx[8];
        #pragma unroll
        for (int i = 0; i < 8; i++) mx[i] = fmaxf(sv[i], sv[i+8]);
        #pragma unroll
        for (int i = 0; i < 4; i++) mx[i] = fmaxf(mx[i], mx[i+4]);
        float tm = fmaxf(fmaxf(mx[0], mx[1]), fmaxf(mx[2], mx[3]));
        tm = fmaxf(tm, __shfl_xor(tm, 16));
        tm = fmaxf(tm, __shfl_xor(tm, 32));

        if (!__all(tm <= m + 8.f)) {        // defer-max: rescale rarely
            float mn = fmaxf(m, tm);
            float corr = __expf(m - mn);
            m = mn; l *= corr;
            if (lane < 16) cb[w][lane] = corr;
            __builtin_amdgcn_s_waitcnt(0);
            const float* cp = &cb[w][grp*4];
            #pragma unroll
            for (int j = 0; j < 4; j++) o[j] *= cp[j];
        }

        float pv[16];
        #pragma unroll
        for (int i = 0; i < 16; i++) pv[i] = __expf(sv[i] - m);
        float sm[8];
        #pragma unroll
        for (int i = 0; i < 8; i++) sm[i] = pv[i] + pv[i+8];
        #pragma unroll
        for (int i = 0; i < 4; i++) sm[i] += sm[i+4];
        float ls = (sm[0] + sm[1]) + (sm[2] + sm[3]);
        ls += __shfl_xor(ls, 16);
        ls += __shfl_xor(ls, 32);
        l += ls;

        {   // pack P -> per-wave LDS
            uint* pb32 = (uint*)Pb[w];
            #pragma unroll
            for (int sub = 0; sub < 4; sub++) {
                uint u01 = (uint)f2bf(pv[sub*4+0]) | ((uint)f2bf(pv[sub*4+1]) << 16);
                uint u23 = (uint)f2bf(pv[sub*4+2]) | ((uint)f2bf(pv[sub*4+3]) << 16);
                int sa = qrow*72 + sub*16 + grp*4;
                *(uint2*)&pb32[sa >> 1] = make_uint2(u01, u23);
            }
        }
        #pragma unroll
        for (int ks = 0; ks < 2; ks++) {
            s16x8 pa = *(const s16x8*)&Pb[w][qrow*72 + ks*32 + grp*8];
            s16x8 cf = *(const s16x8*)&Ch[qrow*72 + ks*32 + grp*8];
            o = __builtin_amdgcn_mfma_f32_16x16x32_bf16(pa, cf, o, 0, 0, 0);
        }
    }

    // ---- merge 4 quarters via LDS partials (overlay Kt: 8*16*18*4 = 9216 B)
    __syncthreads();
    float* part = (float*)Kt;
    if (lane < 16) { part[(w*16+lane)*18 + 0] = m; part[(w*16+lane)*18 + 1] = l; }
    #pragma unroll
    for (int j = 0; j < 4; j++) part[(w*16 + grp*4 + j)*18 + 2 + qrow] = o[j];
    __syncthreads();
    if (w < 2) {
        int q = qrow;
        float M = -1e30f;
        #pragma unroll
        for (int qt = 0; qt < 4; qt++) M = fmaxf(M, part[((qt*2+w)*16 + q)*18]);
        float L = 0.f, v[4] = {0.f,0.f,0.f,0.f};
        #pragma unroll
        for (int qt = 0; qt < 4; qt++) {
            const float* pp = &part[((qt*2+w)*16 + q)*18];
            float ee = __expf(pp[0] - M);
            L += ee * pp[1];
            #pragma unroll
            for (int dd = 0; dd < 4; dd++) v[dd] += ee * pp[2 + grp*4 + dd];
        }
        float inv = 1.f / L;
        int b = bh >> 2, h = bh & 3;
        int s = blockIdx.x * 32 + w * 16 + q;
        #pragma unroll
        for (int dd = 0; dd < 4; dd++) {
            int d = grp*4 + dd;
            if (d < 14)
                wua[SXOB + ((size_t)b*2048 + s)*112 + h*14 + d] = f2bf(fmaxf(v[dd]*inv, 0.f));
        }
    }
}

extern "C" void kernel_launch(void* const* d_in, const int* in_sizes, int n_in,
                              void* d_out, int out_size, void* d_ws, size_t ws_size,
                              hipStream_t stream) {
    const float* x    = (const float*)d_in[0];
    const float* w1   = (const float*)d_in[1];
    const float* w2a  = (const float*)d_in[2];
    const float* w2b  = (const float*)d_in[3];
    const float* w3a  = (const float*)d_in[4];
    const float* w3b  = (const float*)d_in[5];
    const float* w3c  = (const float*)d_in[6];
    const float* g1   = (const float*)d_in[7];
    const float* g2a  = (const float*)d_in[8];
    const float* g2b  = (const float*)d_in[9];
    const float* g3a  = (const float*)d_in[10];
    const float* g3b  = (const float*)d_in[11];
    const float* g3c  = (const float*)d_in[12];
    const float* b1   = (const float*)d_in[13];
    const float* b2a  = (const float*)d_in[14];
    const float* b2b  = (const float*)d_in[15];
    const float* b3a  = (const float*)d_in[16];
    const float* b3b  = (const float*)d_in[17];
    const float* b3c  = (const float*)d_in[18];
    const float* Wmp  = (const float*)d_in[19];
    const float* bmp  = (const float*)d_in[20];
    const float* Wq   = (const float*)d_in[21];
    const float* Wk   = (const float*)d_in[22];
    const float* Wv   = (const float*)d_in[23];
    const float* Wout = (const float*)d_in[24];
    const float* bout = (const float*)d_in[25];
    float* ws = (float*)d_ws;
    float* out = (float*)d_out;
    u16* wu = (u16*)d_ws;

    prepk<<<3850, 256, 0, stream>>>(x, w1, w2a, w2b, w3a, w3b, w3c,
                                    g1, g2a, g2b, g3a, g3b, g3c,
                                    b1, b2a, b3a, Wmp, Wq, Wk, Wv, Wout, ws);

    {   // conv1: xb @ WB1 -> XCATb, bias BCAT, relu
        GemmChunks c{}; c.soff[0]=SXB; c.stride[0]=88; c.shift[0]=0; c.cols[0]=88;
        gemmk<1,0,1><<<dim3(128,5), 256, 0, stream>>>(c, wu, wu+SB1, nullptr, 96,
            ws+OFF_BCAT, nullptr, nullptr, 1, wu+SXCAT, nullptr, nullptr, 264, 264);
    }
    {   // conv3a + conv3b fused
        GemmChunks c{};
        for (int t = 0; t < 3; t++) { c.soff[t]=SXCAT+88; c.stride[t]=264; c.shift[t]=t-1; c.cols[t]=88; }
        gemmk<3,2,1><<<dim3(128,4), 256, 0, stream>>>(c, wu, wu+SB2B, wu+SB3B, 288,
            b2b, b3b, nullptr, 1, wu+SX2, wu+ST3B, nullptr, 88, 88);
    }
    {   // conv5: T3Bb @ WB3C -> X3b
        GemmChunks c{};
        for (int t = 0; t < 5; t++) { c.soff[t]=ST3B; c.stride[t]=88; c.shift[t]=t-2; c.cols[t]=88; }
        gemmk<5,0,1><<<dim3(128,2), 256, 0, stream>>>(c, wu, wu+SB3C, nullptr, 480,
            b3c, nullptr, nullptr, 1, wu+SX3, nullptr, nullptr, 88, 88);
    }
    {   // mp: cat @ WBMP + bmp + x -> MPb (bf16) + MP (fp32)
        GemmChunks c{};
        c.soff[0]=SXCAT; c.stride[0]=264; c.shift[0]=0; c.cols[0]=88;
        c.soff[1]=SX2;   c.stride[1]=88;  c.shift[1]=0; c.cols[1]=88;
        c.soff[2]=SX3;   c.stride[2]=88;  c.shift[2]=0; c.cols[2]=88;
        gemmk<3,0,3><<<dim3(128,2), 256, 0, stream>>>(c, wu, wu+SBMP, nullptr, 288,
            bmp, nullptr, x, 0, wu+SMPB, nullptr, ws+OFF_MP, 88, 88);
    }
    {   // qkv: MPb @ WBQKV -> Qb/Kb bf16 (+pad zeros) + V fp32
        GemmChunks c{}; c.soff[0]=SMPB; c.stride[0]=88; c.shift[0]=0; c.cols[0]=88;
        gemmk<1,1,0><<<dim3(128,6), 256, 0, stream>>>(c, wu, wu+SBQKV, nullptr, 96,
            nullptr, nullptr, nullptr, 0, wu, nullptr, ws, 0, 0);
    }
    dwtk<<<256, 256, 0, stream>>>(ws);
    attnk<<<dim3(64, 16), 512, 0, stream>>>(ws);
    {   // final: XOb @ WBOUT + bout + MP -> out
        GemmChunks c{};
        c.soff[0]=SXOB;    c.stride[0]=112; c.shift[0]=0; c.cols[0]=96;
        c.soff[1]=SXOB+96; c.stride[1]=112; c.shift[1]=0; c.cols[1]=16;
        gemmk<2,0,2><<<dim3(128,2), 256, 0, stream>>>(c, wu, wu+SBOUT, nullptr, 192,
            bout, nullptr, ws+OFF_MP, 0, nullptr, nullptr, out, 88, 88);
    }
}

// Round 11
// 197.303 us; speedup vs baseline: 1.0387x; 1.0387x over previous
//
#include <hip/hip_runtime.h>

#define BN_INV  0.99999500003749981f
#define QSCALE  0.21320071635561041f   // 22^-0.5

typedef unsigned int uint;
typedef unsigned short u16;
typedef __attribute__((ext_vector_type(8))) short s16x8;
typedef __attribute__((ext_vector_type(4))) float f32x4;

// ---- ws layout ----
// float offsets:
#define OFF_BCAT 0         // 264
#define OFF_V    512       // 8192*88 fp32 (qkv out, dwt in)
#define OFF_MP   721408    // 8192*88 fp32 (final residual)   ends 1442304 fl
// short offsets (shorts region starts at 2884608 sh):
#define SW0    2884608
#define SB1    (SW0)            // 320 x 96
#define SB2B   (SW0+30720)      // 128 x 288
#define SB3B   (SW0+67584)      // 128 x 288
#define SB3C   (SW0+104448)     // 128 x 480
#define SBMP   (SW0+165888)     // 128 x 288
#define SBQKV  (SW0+202752)     // 384 x 96
#define SBOUT  (SW0+239616)     // 128 x 192  ends SW0+264192
#define SXB    3148800     // xb   [8192][88]  dead after conv1
#define SXCAT  3869696     // XCAT [8192][264] dead after mp
#define SX2    6032384     // X2   [8192][88]  dead after mp
#define ST3B   6753280     // T3B  [8192][88]  dead after conv5
#define SX3    7474176     // X3   [8192][88]  dead after mp
#define SMPB   8195072     // MPb  [8192][88]  dead after qkv  ends 8915968
// overlays (written after their hosts die):
#define SQB    3869696     // Qb  [16][2048][32]  (over XCAT)
#define SKB    4918272     // Kb  [16][2048][32]  (over XCAT)
#define SCDT   5966848     // CDT [16][16][2048]  (over XCAT tail + X2)
#define SXOB   6753280     // XOb [8192][112]     (over T3B + X3 head)

__constant__ float c_dlo[8] = {-0.010597401784997278f, 0.032883011666982945f,
    0.030841381835986965f, -0.18703481171888114f, -0.02798376941698385f,
    0.6308807679295904f, 0.7148465705525415f, 0.23037781330885523f};
__constant__ float c_dhi[8] = {-0.23037781330885523f, 0.7148465705525415f,
    -0.6308807679295904f, -0.02798376941698385f, 0.18703481171888114f,
    0.030841381835986965f, -0.032883011666982945f, -0.010597401784997278f};

__device__ __forceinline__ u16 f2bf(float f) {
    uint u = __float_as_uint(f);
    uint r = u + 0x7fffu + ((u >> 16) & 1u);
    return (u16)(r >> 16);
}

// ---------------- weight prep + x->bf16 ----------------------------------
__global__ __launch_bounds__(256) void prepk(
    const float* __restrict__ x,
    const float* __restrict__ w1, const float* __restrict__ w2a, const float* __restrict__ w2b,
    const float* __restrict__ w3a, const float* __restrict__ w3b, const float* __restrict__ w3c,
    const float* __restrict__ g1, const float* __restrict__ g2a, const float* __restrict__ g2b,
    const float* __restrict__ g3a, const float* __restrict__ g3b, const float* __restrict__ g3c,
    const float* __restrict__ b1, const float* __restrict__ b2a, const float* __restrict__ b3a,
    const float* __restrict__ Wmp, const float* __restrict__ Wq, const float* __restrict__ Wk,
    const float* __restrict__ Wv, const float* __restrict__ Wout, float* __restrict__ ws)
{
    u16* wu = (u16*)ws;
    int r = blockIdx.x * 256 + threadIdx.x;
    if (r < 264) {
        ws[OFF_BCAT + r] = (r < 88) ? b1[r] : (r < 176 ? b2a[r-88] : b3a[r-176]);
        return;
    }
    r -= 264;
    if (r < 320*96) {                       // WB1: cat(w1,w2a,w3a) folded
        int n = r / 96, kk = r % 96; float v = 0.f;
        if (kk < 88 && n < 264) {
            if (n < 88)       v = w1 [n*88+kk]       * g1 [n];
            else if (n < 176) v = w2a[(n-88)*88+kk]  * g2a[n-88];
            else              v = w3a[(n-176)*88+kk] * g3a[n-176];
            v *= BN_INV;
        }
        wu[SB1 + r] = f2bf(v); return;
    }
    r -= 320*96;
    if (r < 128*288) {                      // WB2B
        int n = r / 288, kk = r % 288, t = kk/96, i = kk%96; float v = 0.f;
        if (n < 88 && i < 88) v = w2b[n*264 + i*3 + t] * g2b[n] * BN_INV;
        wu[SB2B + r] = f2bf(v); return;
    }
    r -= 128*288;
    if (r < 128*288) {                      // WB3B
        int n = r / 288, kk = r % 288, t = kk/96, i = kk%96; float v = 0.f;
        if (n < 88 && i < 88) v = w3b[n*264 + i*3 + t] * g3b[n] * BN_INV;
        wu[SB3B + r] = f2bf(v); return;
    }
    r -= 128*288;
    if (r < 128*480) {                      // WB3C
        int n = r / 480, kk = r % 480, t = kk/96, i = kk%96; float v = 0.f;
        if (n < 88 && i < 88) v = w3c[n*440 + i*5 + t] * g3c[n] * BN_INV;
        wu[SB3C + r] = f2bf(v); return;
    }
    r -= 128*480;
    if (r < 128*288) {                      // WBMP
        int n = r / 288, kk = r % 288, c = kk/96, i = kk%96; float v = 0.f;
        if (n < 88 && i < 88) v = Wmp[n*264 + c*88 + i];
        wu[SBMP + r] = f2bf(v); return;
    }
    r -= 128*288;
    if (r < 384*96) {                       // WBQKV (q-scale folded)
        int n = r / 96, kk = r % 96, sec = n / 128, o = n % 128; float v = 0.f;
        if (o < 88 && kk < 88) {
            if (sec == 0)      v = Wq[o*88+kk] * QSCALE;
            else if (sec == 1) v = Wk[o*88+kk];
            else               v = Wv[o*88+kk];
        }
        wu[SBQKV + r] = f2bf(v); return;
    }
    r -= 384*96;
    if (r < 128*192) {                      // WBOUT
        int n = r / 192, kk = r % 192; float v = 0.f;
        if (n < 88 && kk < 112) v = Wout[n*112 + kk];
        wu[SBOUT + r] = f2bf(v); return;
    }
    r -= 128*192;
    if (r < 8192*88) {                      // xb
        wu[SXB + r] = f2bf(x[r]); return;
    }
}

// ------- bf16 MFMA GEMM, 64x64 tile, single-stage (all K in LDS) ----------
struct GemmChunks {
    int soff[5];    // short offset of bf16 source base (per chunk)
    int stride[5];  // in shorts
    int cols[5];    // valid cols (<=96)
};

// HALO=1: one source, chunks are row-shifts (rows staged once with halo).
// HALO=0: NCH distinct sources, each staged to its own LDS panel.
// MODE 0: normal; MODE 1: qkv scatter (+Q/K pad zero); MODE 2: dual conv3.
// OUTM bit0: write bf16 outb; bit1: write fp32 outf
template<int NCH, int HALO, int MODE, int OUTM>
__global__ __launch_bounds__(256) void gemmk(GemmChunks ch,
    const u16* __restrict__ wsrc,
    const u16* __restrict__ Bw, const u16* __restrict__ Bw2,
    const float* __restrict__ bias, const float* __restrict__ bias2,
    const float* __restrict__ resid, int relu,
    u16* __restrict__ outb, u16* __restrict__ outb2,
    float* __restrict__ outf, int outStride, int N)
{
    constexpr int RA   = HALO ? (64 + NCH - 1) : 64 * NCH;   // A rows staged
    constexpr int BSTR = NCH * 96 + 8;                       // B row stride
    constexpr int KTOT = NCH * 96;
    __shared__ u16 As[RA * 104];
    __shared__ u16 Bs[64 * BSTR];
    int tid = threadIdx.x;
    int lane = tid & 63, w = tid >> 6, wr = w >> 1, wc = w & 1;
    int p0 = blockIdx.x * 64;
    int nb = blockIdx.y;
    int which = (MODE == 2) ? (nb >> 1) : 0;
    int nbl   = (MODE == 2) ? (nb & 1) : nb;
    const u16* Bw_ = (MODE == 2 && which) ? Bw2 : Bw;
    int bs = p0 & ~2047, be = bs + 2048;

    // ---- stage A (once) ----
    if (HALO) {
        constexpr int OFS = (NCH - 1) / 2;
        int soff = ch.soff[0] + which * 88;
        int stride = ch.stride[0], cols = ch.cols[0];
        for (int e = tid; e < RA * 12; e += 256) {
            int r = e / 12, seg = e % 12;
            int row = p0 + r - OFS;
            int4 v = {0,0,0,0};
            if (row >= bs && row < be && seg*8 < cols)
                v = *(const int4*)&wsrc[(size_t)soff + (size_t)row*stride + seg*8];
            *(int4*)&As[r*104 + seg*8] = v;
        }
    } else {
        for (int e = tid; e < NCH * 768; e += 256) {
            int c = e / 768, rem = e - c*768;
            int r = rem / 12, seg = rem % 12;
            int row = p0 + r;
            int4 v = {0,0,0,0};
            if (seg*8 < ch.cols[c])
                v = *(const int4*)&wsrc[(size_t)ch.soff[c] + (size_t)row*ch.stride[c] + seg*8];
            *(int4*)&As[c*6656 + r*104 + seg*8] = v;
        }
    }
    // ---- stage B (all chunks) ----
    for (int e = tid; e < 64 * NCH * 12; e += 256) {
        int n = e / (NCH*12), seg = e % (NCH*12);
        *(int4*)&Bs[n*BSTR + seg*8] =
            *(const int4*)&Bw_[((size_t)(nbl*64 + n))*KTOT + seg*8];
    }
    __syncthreads();

    f32x4 acc[2][2];
    #pragma unroll
    for (int a = 0; a < 2; a++)
        #pragma unroll
        for (int b = 0; b < 2; b++) acc[a][b] = (f32x4){0.f,0.f,0.f,0.f};

    int ar0 = (wr*32 + (lane&15))*104 + (lane>>4)*8;
    int br0 = (wc*32 + (lane&15))*BSTR + (lane>>4)*8;

    #pragma unroll
    for (int c = 0; c < NCH; c++) {
        int abase = HALO ? (ar0 + c*104) : (c*6656 + ar0);
        int bbase = br0 + c*96;
        #pragma unroll
        for (int ks = 0; ks < 3; ks++) {
            s16x8 a0 = *(const s16x8*)&As[abase + ks*32];
            s16x8 a1 = *(const s16x8*)&As[abase + 16*104 + ks*32];
            s16x8 b0 = *(const s16x8*)&Bs[bbase + ks*32];
            s16x8 b1 = *(const s16x8*)&Bs[bbase + 16*BSTR + ks*32];
            acc[0][0] = __builtin_amdgcn_mfma_f32_16x16x32_bf16(a0, b0, acc[0][0], 0, 0, 0);
            acc[0][1] = __builtin_amdgcn_mfma_f32_16x16x32_bf16(a0, b1, acc[0][1], 0, 0, 0);
            acc[1][0] = __builtin_amdgcn_mfma_f32_16x16x32_bf16(a1, b0, acc[1][0], 0, 0, 0);
            acc[1][1] = __builtin_amdgcn_mfma_f32_16x16x32_bf16(a1, b1, acc[1][1], 0, 0, 0);
        }
    }

    int rbase = p0 + wr*32 + (lane>>4)*4;
    if (MODE != 1) {
        u16* outb_ = (MODE == 2 && which) ? outb2 : outb;
        const float* bias_ = (MODE == 2 && which) ? bias2 : bias;
        int cbase = nbl*64 + wc*32 + (lane&15);
        #pragma unroll
        for (int fn = 0; fn < 2; fn++) {
            int col = cbase + fn*16;
            if (col < N) {
                float bb = bias_ ? bias_[col] : 0.f;
                #pragma unroll
                for (int fm = 0; fm < 2; fm++)
                    #pragma unroll
                    for (int j = 0; j < 4; j++) {
                        int row = rbase + fm*16 + j;
                        float v = acc[fm][fn][j] + bb;
                        if (relu) v = fmaxf(v, 0.f);
                        if (resid) v += resid[(size_t)row*outStride + col];
                        if (OUTM & 1) outb_[(size_t)row*outStride + col] = f2bf(v);
                        if (OUTM & 2) outf[(size_t)row*outStride + col] = v;
                    }
            }
        }
    } else {
        u16* wq = outb;    // wu base
        int sec = nb >> 1;
        #pragma unroll
        for (int fn = 0; fn < 2; fn++) {
            int cw = (nb&1)*64 + wc*32 + fn*16 + (lane&15);
            if (cw < 88) {
                int h = cw / 22, d = cw % 22;
                #pragma unroll
                for (int fm = 0; fm < 2; fm++)
                    #pragma unroll
                    for (int j = 0; j < 4; j++) {
                        int row = rbase + fm*16 + j;
                        int b = row >> 11, s = row & 2047;
                        float v = acc[fm][fn][j];
                        if (sec == 0)
                            wq[SQB + ((size_t)(b*4+h)*2048 + s)*32 + d] = f2bf(v);
                        else if (sec == 1)
                            wq[SKB + ((size_t)(b*4+h)*2048 + s)*32 + d] = f2bf(v);
                        else
                            outf[OFF_V + (size_t)row*88 + cw] = v;
                    }
            } else if (sec < 2 && cw < 128) {
                // idle cols zero the Q/K pads d=22..31 (40 slots = 4h x 10d)
                int t = cw - 88, h = t / 10, dpad = 22 + t % 10;
                size_t sqk = (sec == 0) ? (size_t)SQB : (size_t)SKB;
                #pragma unroll
                for (int fm = 0; fm < 2; fm++)
                    #pragma unroll
                    for (int j = 0; j < 4; j++) {
                        int row = rbase + fm*16 + j;
                        int b = row >> 11, s = row & 2047;
                        wq[sqk + ((size_t)(b*4+h)*2048 + s)*32 + dpad] = 0;
                    }
            }
        }
    }
}

// ---------------- DWT(V) -> CDT bf16 + cA scatter (s-fast, coalesced) -----
__global__ __launch_bounds__(256) void dwtk(float* __restrict__ ws)
{
    u16* wu = (u16*)ws;
    __shared__ float vs[32*89];             // 32 pos x 88, pad 89 (bank-clean)
    int tid = threadIdx.x;
    int p0 = blockIdx.x * 32;
    const float* V = ws + OFF_V;
    for (int e = tid; e < 32*88; e += 256) {
        int p = e / 88, c = e - p*88;
        vs[p*89 + c] = V[(size_t)p0*88 + e];
    }
    __syncthreads();
    int b = p0 >> 11, sbase = p0 & 2047;
    #pragma unroll
    for (int it = 0; it < 7; it++) {
        int idx = it*256 + tid;             // 1792 = 32 pos x 56 (h,jj)
        int p = idx & 31, hjj = idx >> 5;
        int h = hjj / 14, jj = hjj - h*14;
        const float* v = &vs[p*89 + h*22];
        float ca = 0.f, cd = 0.f;
        #pragma unroll
        for (int t = 0; t < 8; t++) {
            int pp = 1 + 2*jj + t;
            int oi = pp < 7 ? 6 - pp : (pp < 29 ? pp - 7 : 50 - pp);
            float vv = v[oi];
            ca = fmaf(vv, c_dlo[7-t], ca);
            cd = fmaf(vv, c_dhi[7-t], cd);
        }
        int s = sbase + p;
        wu[SCDT + ((size_t)((b*4+h)*16 + jj))*2048 + s] = f2bf(cd);   // s-fast
        int hs = h*2048 + s, s2 = hs >> 2, qd = hs & 3;
        wu[SXOB + ((size_t)b*2048 + s2)*112 + 56 + qd*14 + jj] = f2bf(ca);
    }
    {   // CDT pad rows d=14,15 (256 writes, s-fast)
        int p = tid & 31, t = tid >> 5;
        int h = t >> 1, dd = 14 + (t & 1);
        wu[SCDT + ((size_t)((b*4+h)*16 + dd))*2048 + sbase + p] = 0;
    }
}

// ---- MFMA flash attention, 2-way split-K + defer-max + reg prefetch ------
// 512 thr = 8 waves; grid (32 q-tiles, 16 bh). Wave w: q-sub (w&3), key-half
// (w>>2) of 1024 keys in 16 tiles of 64. Partials merged in LDS.
__global__ __launch_bounds__(512, 4) void attnk(float* __restrict__ ws)
{
    const u16* wu = (const u16*)ws;
    u16* wua = (u16*)ws;
    __shared__ __align__(16) u16 Kt[2*64*40];      // [half][key64][40]
    __shared__ __align__(16) u16 CDt[2*16*72];     // [half][d16][72]
    __shared__ __align__(16) u16 Pb[8][16*72];     // per-wave P
    int tid = threadIdx.x, lane = tid & 63, w = tid >> 6;
    int bh = blockIdx.y;
    int qsub = w & 3, half = w >> 2;
    int q0 = blockIdx.x * 64 + qsub * 16;
    int qrow = lane & 15, grp = lane >> 4;

    s16x8 qf = *(const s16x8*)&wu[SQB + ((size_t)bh*2048 + q0 + qrow)*32 + grp*8];
    const u16* Kbase = wu + SKB + (size_t)bh*2048*32;
    const u16* Cbase = wu + SCDT + (size_t)bh*16*2048;
    const u16* Kh = &Kt[half*2560];
    const u16* Ch = &CDt[half*1152];

    // staging thread->slot mapping
    int khh = tid >> 8, krr = (tid >> 2) & 63, kseg = tid & 3;
    int chh = tid >> 7, cdd = (tid >> 3) & 15, cseg = tid & 7;   // tid<256

    f32x4 o = (f32x4){0.f,0.f,0.f,0.f};
    float m = -1e30f, l = 0.f;

    // prologue: prefetch tile 0 into regs
    int4 kreg = *(const int4*)&Kbase[(size_t)(khh*1024 + krr)*32 + kseg*8];
    int4 creg = {0,0,0,0};
    if (tid < 256)
        creg = *(const int4*)&Cbase[(size_t)cdd*2048 + chh*1024 + cseg*8];

    for (int kt = 0; kt < 16; kt++) {
        __syncthreads();                    // prev tile's LDS reads done
        *(int4*)&Kt[khh*2560 + krr*40 + kseg*8] = kreg;
        if (tid < 256) *(int4*)&CDt[chh*1152 + cdd*72 + cseg*8] = creg;
        __syncthreads();
        if (kt < 15) {                      // prefetch next tile under compute
            kreg = *(const int4*)&Kbase[(size_t)(khh*1024 + (kt+1)*64 + krr)*32 + kseg*8];
            if (tid < 256)
                creg = *(const int4*)&Cbase[(size_t)cdd*2048 + chh*1024 + (kt+1)*64 + cseg*8];
        }

        f32x4 s4[4];
        #pragma unroll
        for (int sub = 0; sub < 4; sub++) {
            s16x8 kf = *(const s16x8*)&Kh[(sub*16 + qrow)*40 + grp*8];
            s4[sub] = __builtin_amdgcn_mfma_f32_16x16x32_bf16(kf, qf,
                        (f32x4){0.f,0.f,0.f,0.f}, 0, 0, 0);
        }
        float sv[16];
        #pragma unroll
        for (int sub = 0; sub < 4; sub++)
            #pragma unroll
            for (int j = 0; j < 4; j++) sv[sub*4+j] = s4[sub][j];

        float mx[8];
        #pragma unroll
        for (int i = 0; i < 8; i++) mx[i] = fmaxf(sv[i], sv[i+8]);
        #pragma unroll
        for (int i = 0; i < 4; i++) mx[i] = fmaxf(mx[i], mx[i+4]);
        float tm = fmaxf(fmaxf(mx[0], mx[1]), fmaxf(mx[2], mx[3]));
        tm = fmaxf(tm, __shfl_xor(tm, 16));
        tm = fmaxf(tm, __shfl_xor(tm, 32));

        if (!__all(tm <= m + 8.f)) {        // defer-max: rescale rarely
            float mn = fmaxf(m, tm);
            float corr = __expf(m - mn);
            m = mn; l *= corr;
            // corr for q=grp*4+j lives at lane grp*4+j (q=lane&15 layout)
            #pragma unroll
            for (int j = 0; j < 4; j++) o[j] *= __shfl(corr, grp*4 + j);
        }

        float pv[16];
        #pragma unroll
        for (int i = 0; i < 16; i++) pv[i] = __expf(sv[i] - m);
        float sm[8];
        #pragma unroll
        for (int i = 0; i < 8; i++) sm[i] = pv[i] + pv[i+8];
        #pragma unroll
        for (int i = 0; i < 4; i++) sm[i] += sm[i+4];
        float ls = (sm[0] + sm[1]) + (sm[2] + sm[3]);
        ls += __shfl_xor(ls, 16);
        ls += __shfl_xor(ls, 32);
        l += ls;

        {   // pack P -> per-wave LDS
            uint* pb32 = (uint*)Pb[w];
            #pragma unroll
            for (int sub = 0; sub < 4; sub++) {
                uint u01 = (uint)f2bf(pv[sub*4+0]) | ((uint)f2bf(pv[sub*4+1]) << 16);
                uint u23 = (uint)f2bf(pv[sub*4+2]) | ((uint)f2bf(pv[sub*4+3]) << 16);
                int sa = qrow*72 + sub*16 + grp*4;
                *(uint2*)&pb32[sa >> 1] = make_uint2(u01, u23);
            }
        }
        #pragma unroll
        for (int ks = 0; ks < 2; ks++) {
            s16x8 pa = *(const s16x8*)&Pb[w][qrow*72 + ks*32 + grp*8];
            s16x8 cf = *(const s16x8*)&Ch[qrow*72 + ks*32 + grp*8];
            o = __builtin_amdgcn_mfma_f32_16x16x32_bf16(pa, cf, o, 0, 0, 0);
        }
    }

    // ---- merge halves via LDS partials (overlay Kt: 8*16*18 f32 = 9216 B)
    __syncthreads();
    float* part = (float*)Kt;
    if (lane < 16) { part[(w*16+lane)*18 + 0] = m; part[(w*16+lane)*18 + 1] = l; }
    #pragma unroll
    for (int j = 0; j < 4; j++) part[(w*16 + grp*4 + j)*18 + 2 + qrow] = o[j];
    __syncthreads();
    if (w < 4) {
        int q = qrow;
        const float* pa = &part[(w*16 + q)*18];
        const float* pb = &part[((w+4)*16 + q)*18];
        float m0 = pa[0], l0 = pa[1], m1 = pb[0], l1 = pb[1];
        float M = fmaxf(m0, m1);
        float e0 = __expf(m0 - M), e1 = __expf(m1 - M);
        float inv = 1.f / (l0*e0 + l1*e1);
        int b = bh >> 2, h = bh & 3;
        int s = blockIdx.x * 64 + w * 16 + q;
        #pragma unroll
        for (int dd = 0; dd < 4; dd++) {
            int d = grp*4 + dd;
            if (d < 14) {
                float val = (pa[2+d]*e0 + pb[2+d]*e1) * inv;
                wua[SXOB + ((size_t)b*2048 + s)*112 + h*14 + d] = f2bf(fmaxf(val, 0.f));
            }
        }
    }
}

extern "C" void kernel_launch(void* const* d_in, const int* in_sizes, int n_in,
                              void* d_out, int out_size, void* d_ws, size_t ws_size,
                              hipStream_t stream) {
    const float* x    = (const float*)d_in[0];
    const float* w1   = (const float*)d_in[1];
    const float* w2a  = (const float*)d_in[2];
    const float* w2b  = (const float*)d_in[3];
    const float* w3a  = (const float*)d_in[4];
    const float* w3b  = (const float*)d_in[5];
    const float* w3c  = (const float*)d_in[6];
    const float* g1   = (const float*)d_in[7];
    const float* g2a  = (const float*)d_in[8];
    const float* g2b  = (const float*)d_in[9];
    const float* g3a  = (const float*)d_in[10];
    const float* g3b  = (const float*)d_in[11];
    const float* g3c  = (const float*)d_in[12];
    const float* b1   = (const float*)d_in[13];
    const float* b2a  = (const float*)d_in[14];
    const float* b2b  = (const float*)d_in[15];
    const float* b3a  = (const float*)d_in[16];
    const float* b3b  = (const float*)d_in[17];
    const float* b3c  = (const float*)d_in[18];
    const float* Wmp  = (const float*)d_in[19];
    const float* bmp  = (const float*)d_in[20];
    const float* Wq   = (const float*)d_in[21];
    const float* Wk   = (const float*)d_in[22];
    const float* Wv   = (const float*)d_in[23];
    const float* Wout = (const float*)d_in[24];
    const float* bout = (const float*)d_in[25];
    float* ws = (float*)d_ws;
    float* out = (float*)d_out;
    u16* wu = (u16*)d_ws;

    prepk<<<3850, 256, 0, stream>>>(x, w1, w2a, w2b, w3a, w3b, w3c,
                                    g1, g2a, g2b, g3a, g3b, g3c,
                                    b1, b2a, b3a, Wmp, Wq, Wk, Wv, Wout, ws);

    {   // conv1: xb @ WB1 -> XCATb, bias BCAT, relu
        GemmChunks c{}; c.soff[0]=SXB; c.stride[0]=88; c.cols[0]=88;
        gemmk<1,1,0,1><<<dim3(128,5), 256, 0, stream>>>(c, wu, wu+SB1, nullptr,
            ws+OFF_BCAT, nullptr, nullptr, 1, wu+SXCAT, nullptr, nullptr, 264, 264);
    }
    {   // conv3a + conv3b fused (halo rows staged once)
        GemmChunks c{}; c.soff[0]=SXCAT+88; c.stride[0]=264; c.cols[0]=88;
        gemmk<3,1,2,1><<<dim3(128,4), 256, 0, stream>>>(c, wu, wu+SB2B, wu+SB3B,
            b2b, b3b, nullptr, 1, wu+SX2, wu+ST3B, nullptr, 88, 88);
    }
    {   // conv5: T3Bb @ WB3C -> X3b (halo rows staged once)
        GemmChunks c{}; c.soff[0]=ST3B; c.stride[0]=88; c.cols[0]=88;
        gemmk<5,1,0,1><<<dim3(128,2), 256, 0, stream>>>(c, wu, wu+SB3C, nullptr,
            b3c, nullptr, nullptr, 1, wu+SX3, nullptr, nullptr, 88, 88);
    }
    {   // mp: cat @ WBMP + bmp + x -> MPb (bf16) + MP (fp32)
        GemmChunks c{};
        c.soff[0]=SXCAT; c.stride[0]=264; c.cols[0]=88;
        c.soff[1]=SX2;   c.stride[1]=88;  c.cols[1]=88;
        c.soff[2]=SX3;   c.stride[2]=88;  c.cols[2]=88;
        gemmk<3,0,0,3><<<dim3(128,2), 256, 0, stream>>>(c, wu, wu+SBMP, nullptr,
            bmp, nullptr, x, 0, wu+SMPB, nullptr, ws+OFF_MP, 88, 88);
    }
    {   // qkv: MPb @ WBQKV -> Qb/Kb bf16 (+pad zeros) + V fp32
        GemmChunks c{}; c.soff[0]=SMPB; c.stride[0]=88; c.cols[0]=88;
        gemmk<1,1,1,0><<<dim3(128,6), 256, 0, stream>>>(c, wu, wu+SBQKV, nullptr,
            nullptr, nullptr, nullptr, 0, wu, nullptr, ws, 0, 0);
    }
    dwtk<<<256, 256, 0, stream>>>(ws);
    attnk<<<dim3(32, 16), 512, 0, stream>>>(ws);
    {   // final: XOb @ WBOUT + bout + MP -> out
        GemmChunks c{};
        c.soff[0]=SXOB;    c.stride[0]=112; c.cols[0]=96;
        c.soff[1]=SXOB+96; c.stride[1]=112; c.cols[1]=16;
        gemmk<2,0,0,2><<<dim3(128,2), 256, 0, stream>>>(c, wu, wu+SBOUT, nullptr,
            bout, nullptr, ws+OFF_MP, 0, nullptr, nullptr, out, 88, 88);
    }
}

// Round 12
// 189.084 us; speedup vs baseline: 1.0838x; 1.0435x over previous
//
#include <hip/hip_runtime.h>

#define BN_INV  0.99999500003749981f
#define QSCALE  0.21320071635561041f   // 22^-0.5

typedef unsigned int uint;
typedef unsigned short u16;
typedef __attribute__((ext_vector_type(8))) short s16x8;
typedef __attribute__((ext_vector_type(4))) float f32x4;

// ---- ws layout ----
// float offsets:
#define OFF_BCAT 0         // 264
#define OFF_MP   721408    // 8192*88 fp32 (final residual)
// short offsets:
#define SW0    2884608
#define SB1    (SW0)            // 320 x 96
#define SB2B   (SW0+30720)      // 128 x 288
#define SB3B   (SW0+67584)      // 128 x 288
#define SB3C   (SW0+104448)     // 128 x 480
#define SBMP   (SW0+165888)     // 128 x 288
#define SBQKV  (SW0+202752)     // 384 x 96
#define SBOUT  (SW0+239616)     // 128 x 192
#define SXB    3148800     // xb   [8192][88]
#define SQB    3869696     // Qb  [16][2048][32]
#define SKB    4918272     // Kb  [16][2048][32]
#define SCDT   5966848     // CDT [16][16][2048]
#define SXOB   6753280     // XOb [8192][112]

__constant__ float c_dlo[8] = {-0.010597401784997278f, 0.032883011666982945f,
    0.030841381835986965f, -0.18703481171888114f, -0.02798376941698385f,
    0.6308807679295904f, 0.7148465705525415f, 0.23037781330885523f};
__constant__ float c_dhi[8] = {-0.23037781330885523f, 0.7148465705525415f,
    -0.6308807679295904f, -0.02798376941698385f, 0.18703481171888114f,
    0.030841381835986965f, -0.032883011666982945f, -0.010597401784997278f};

__device__ __forceinline__ u16 f2bf(float f) {
    uint u = __float_as_uint(f);
    uint r = u + 0x7fffu + ((u >> 16) & 1u);
    return (u16)(r >> 16);
}
__device__ __forceinline__ float bf2f(u16 u) {
    return __uint_as_float((uint)u << 16);
}

// ---------------- weight prep + x->bf16 ----------------------------------
__global__ __launch_bounds__(256) void prepk(
    const float* __restrict__ x,
    const float* __restrict__ w1, const float* __restrict__ w2a, const float* __restrict__ w2b,
    const float* __restrict__ w3a, const float* __restrict__ w3b, const float* __restrict__ w3c,
    const float* __restrict__ g1, const float* __restrict__ g2a, const float* __restrict__ g2b,
    const float* __restrict__ g3a, const float* __restrict__ g3b, const float* __restrict__ g3c,
    const float* __restrict__ b1, const float* __restrict__ b2a, const float* __restrict__ b3a,
    const float* __restrict__ Wmp, const float* __restrict__ Wq, const float* __restrict__ Wk,
    const float* __restrict__ Wv, const float* __restrict__ Wout, float* __restrict__ ws)
{
    u16* wu = (u16*)ws;
    int r = blockIdx.x * 256 + threadIdx.x;
    if (r < 264) {
        ws[OFF_BCAT + r] = (r < 88) ? b1[r] : (r < 176 ? b2a[r-88] : b3a[r-176]);
        return;
    }
    r -= 264;
    if (r < 320*96) {                       // WB1: cat(w1,w2a,w3a) folded
        int n = r / 96, kk = r % 96; float v = 0.f;
        if (kk < 88 && n < 264) {
            if (n < 88)       v = w1 [n*88+kk]       * g1 [n];
            else if (n < 176) v = w2a[(n-88)*88+kk]  * g2a[n-88];
            else              v = w3a[(n-176)*88+kk] * g3a[n-176];
            v *= BN_INV;
        }
        wu[SB1 + r] = f2bf(v); return;
    }
    r -= 320*96;
    if (r < 128*288) {                      // WB2B
        int n = r / 288, kk = r % 288, t = kk/96, i = kk%96; float v = 0.f;
        if (n < 88 && i < 88) v = w2b[n*264 + i*3 + t] * g2b[n] * BN_INV;
        wu[SB2B + r] = f2bf(v); return;
    }
    r -= 128*288;
    if (r < 128*288) {                      // WB3B
        int n = r / 288, kk = r % 288, t = kk/96, i = kk%96; float v = 0.f;
        if (n < 88 && i < 88) v = w3b[n*264 + i*3 + t] * g3b[n] * BN_INV;
        wu[SB3B + r] = f2bf(v); return;
    }
    r -= 128*288;
    if (r < 128*480) {                      // WB3C
        int n = r / 480, kk = r % 480, t = kk/96, i = kk%96; float v = 0.f;
        if (n < 88 && i < 88) v = w3c[n*440 + i*5 + t] * g3c[n] * BN_INV;
        wu[SB3C + r] = f2bf(v); return;
    }
    r -= 128*480;
    if (r < 128*288) {                      // WBMP
        int n = r / 288, kk = r % 288, c = kk/96, i = kk%96; float v = 0.f;
        if (n < 88 && i < 88) v = Wmp[n*264 + c*88 + i];
        wu[SBMP + r] = f2bf(v); return;
    }
    r -= 128*288;
    if (r < 384*96) {                       // WBQKV (q-scale folded)
        int n = r / 96, kk = r % 96, sec = n / 128, o = n % 128; float v = 0.f;
        if (o < 88 && kk < 88) {
            if (sec == 0)      v = Wq[o*88+kk] * QSCALE;
            else if (sec == 1) v = Wk[o*88+kk];
            else               v = Wv[o*88+kk];
        }
        wu[SBQKV + r] = f2bf(v); return;
    }
    r -= 384*96;
    if (r < 128*192) {                      // WBOUT
        int n = r / 192, kk = r % 192; float v = 0.f;
        if (n < 88 && kk < 112) v = Wout[n*112 + kk];
        wu[SBOUT + r] = f2bf(v); return;
    }
    r -= 128*192;
    if (r < 8192*88) {                      // xb
        wu[SXB + r] = f2bf(x[r]); return;
    }
}

// ---- MEGA kernel: conv1 -> conv3a/b -> conv5 -> mp -> qkv -> dwt ---------
// 256 blocks x 32 rows, 256 thr = 4 waves. All activations in LDS.
// B fragments read directly from L2-resident weight tables.
__global__ __launch_bounds__(256) void megak(const float* __restrict__ x,
    const float* __restrict__ b2b, const float* __restrict__ b3b,
    const float* __restrict__ b3c, const float* __restrict__ bmp,
    float* __restrict__ ws)
{
    u16* wu = (u16*)ws;
    __shared__ __align__(16) u16 XBs[48*104];    // xb rows p0-3..p0+44; X2s overlay
    __shared__ __align__(16) u16 TC [52*272];    // conv1 out rows p0-3+i
    __shared__ __align__(16) u16 T3Bs[36*104];   // rows p0-2+i
    __shared__ __align__(16) u16 X3s[32*104];
    __shared__ __align__(16) u16 MPBs[32*104];
    __shared__ __align__(16) u16 Vs[32*96];
    u16* X2s = XBs;                              // overlay (XB dead after conv1)

    int tid = threadIdx.x, lane = tid & 63, w = tid >> 6;
    int p0 = blockIdx.x * 32;
    int bs = p0 & ~2047, be = bs + 2048;
    int qrow = lane & 15, grp = lane >> 4;
    int rj = grp * 4;

    // ---- stage xb rows p0-3..p0+44 (48 rows x 96 cols, pad zero) ----
    for (int e = tid; e < 576; e += 256) {
        int r = e / 12, seg = e % 12;
        int grow = p0 - 3 + r;
        int4 v = {0,0,0,0};
        if (seg < 11 && grow >= 0 && grow < 8192)
            v = *(const int4*)&wu[SXB + (size_t)grow*88 + seg*8];
        *(int4*)&XBs[r*104 + seg*8] = v;
    }
    __syncthreads();

    // ---- conv1: TC rows 0..47 (global p0-3+r), cols 0..271 ----
    for (int p = w; p < 51; p += 4) {
        int rt = p % 3, ct = p / 3;
        f32x4 acc = (f32x4){0.f,0.f,0.f,0.f};
        #pragma unroll
        for (int ks = 0; ks < 3; ks++) {
            s16x8 a = *(const s16x8*)&XBs[(rt*16+qrow)*104 + ks*32 + grp*8];
            s16x8 b = *(const s16x8*)&wu[SB1 + (size_t)(ct*16+qrow)*96 + ks*32 + grp*8];
            acc = __builtin_amdgcn_mfma_f32_16x16x32_bf16(a, b, acc, 0, 0, 0);
        }
        int col = ct*16 + qrow;
        float bb = (col < 264) ? ws[OFF_BCAT + col] : 0.f;
        #pragma unroll
        for (int j = 0; j < 4; j++) {
            int r = rt*16 + rj + j;
            int grow = p0 - 3 + r;
            float v = fmaxf(acc[j] + bb, 0.f);
            TC[r*272 + col] = (grow >= bs && grow < be) ? f2bf(v) : (u16)0;
        }
    }
    __syncthreads();

    // ---- conv3a (X2s rows 0..31) + conv3b (T3Bs rows 0..35) ----
    for (int p = w; p < 30; p += 4) {
        if (p < 12) {
            int rt = p % 2, ct = p / 2;
            f32x4 acc = (f32x4){0.f,0.f,0.f,0.f};
            #pragma unroll
            for (int t = 0; t < 3; t++)
                #pragma unroll
                for (int ks = 0; ks < 3; ks++) {
                    s16x8 a = *(const s16x8*)&TC[((2+t) + rt*16+qrow)*272 + 88 + ks*32 + grp*8];
                    s16x8 b = *(const s16x8*)&wu[SB2B + (size_t)(ct*16+qrow)*288 + t*96 + ks*32 + grp*8];
                    acc = __builtin_amdgcn_mfma_f32_16x16x32_bf16(a, b, acc, 0, 0, 0);
                }
            int col = ct*16 + qrow;
            float bb = (col < 88) ? b2b[col] : 0.f;
            #pragma unroll
            for (int j = 0; j < 4; j++) {
                int i = rt*16 + rj + j;
                X2s[i*104 + col] = f2bf(fmaxf(acc[j] + bb, 0.f));
            }
        } else {
            int pp = p - 12, rt = pp % 3, ct = pp / 3;
            f32x4 acc = (f32x4){0.f,0.f,0.f,0.f};
            #pragma unroll
            for (int t = 0; t < 3; t++)
                #pragma unroll
                for (int ks = 0; ks < 3; ks++) {
                    s16x8 a = *(const s16x8*)&TC[(rt*16+qrow + t)*272 + 176 + ks*32 + grp*8];
                    s16x8 b = *(const s16x8*)&wu[SB3B + (size_t)(ct*16+qrow)*288 + t*96 + ks*32 + grp*8];
                    acc = __builtin_amdgcn_mfma_f32_16x16x32_bf16(a, b, acc, 0, 0, 0);
                }
            int col = ct*16 + qrow;
            float bb = (col < 88) ? b3b[col] : 0.f;
            #pragma unroll
            for (int j = 0; j < 4; j++) {
                int i = rt*16 + rj + j;
                if (i < 36) {
                    int grow = p0 - 2 + i;
                    float v = fmaxf(acc[j] + bb, 0.f);
                    T3Bs[i*104 + col] = (grow >= bs && grow < be) ? f2bf(v) : (u16)0;
                }
            }
        }
    }
    __syncthreads();

    // ---- conv5: X3s rows 0..31 ----
    for (int p = w; p < 12; p += 4) {
        int rt = p % 2, ct = p / 2;
        f32x4 acc = (f32x4){0.f,0.f,0.f,0.f};
        #pragma unroll
        for (int t = 0; t < 5; t++)
            #pragma unroll
            for (int ks = 0; ks < 3; ks++) {
                s16x8 a = *(const s16x8*)&T3Bs[(rt*16+qrow + t)*104 + ks*32 + grp*8];
                s16x8 b = *(const s16x8*)&wu[SB3C + (size_t)(ct*16+qrow)*480 + t*96 + ks*32 + grp*8];
                acc = __builtin_amdgcn_mfma_f32_16x16x32_bf16(a, b, acc, 0, 0, 0);
            }
        int col = ct*16 + qrow;
        float bb = (col < 88) ? b3c[col] : 0.f;
        #pragma unroll
        for (int j = 0; j < 4; j++) {
            int i = rt*16 + rj + j;
            X3s[i*104 + col] = f2bf(fmaxf(acc[j] + bb, 0.f));
        }
    }
    __syncthreads();

    // ---- mp: MPBs bf16 + MP fp32 (resid for final) ----
    for (int p = w; p < 12; p += 4) {
        int rt = p % 2, ct = p / 2;
        f32x4 acc = (f32x4){0.f,0.f,0.f,0.f};
        #pragma unroll
        for (int ks = 0; ks < 3; ks++) {
            s16x8 a = *(const s16x8*)&TC[(3 + rt*16+qrow)*272 + ks*32 + grp*8];
            s16x8 b = *(const s16x8*)&wu[SBMP + (size_t)(ct*16+qrow)*288 + ks*32 + grp*8];
            acc = __builtin_amdgcn_mfma_f32_16x16x32_bf16(a, b, acc, 0, 0, 0);
        }
        #pragma unroll
        for (int ks = 0; ks < 3; ks++) {
            s16x8 a = *(const s16x8*)&X2s[(rt*16+qrow)*104 + ks*32 + grp*8];
            s16x8 b = *(const s16x8*)&wu[SBMP + (size_t)(ct*16+qrow)*288 + 96 + ks*32 + grp*8];
            acc = __builtin_amdgcn_mfma_f32_16x16x32_bf16(a, b, acc, 0, 0, 0);
        }
        #pragma unroll
        for (int ks = 0; ks < 3; ks++) {
            s16x8 a = *(const s16x8*)&X3s[(rt*16+qrow)*104 + ks*32 + grp*8];
            s16x8 b = *(const s16x8*)&wu[SBMP + (size_t)(ct*16+qrow)*288 + 192 + ks*32 + grp*8];
            acc = __builtin_amdgcn_mfma_f32_16x16x32_bf16(a, b, acc, 0, 0, 0);
        }
        int col = ct*16 + qrow;
        float bb = (col < 88) ? bmp[col] : 0.f;
        #pragma unroll
        for (int j = 0; j < 4; j++) {
            int i = rt*16 + rj + j;
            float v = acc[j] + bb;
            if (col < 88) {
                v += x[(size_t)(p0+i)*88 + col];
                ws[OFF_MP + (size_t)(p0+i)*88 + col] = v;
            } else v = 0.f;
            MPBs[i*104 + col] = f2bf(v);
        }
    }
    __syncthreads();

    // ---- qkv: Q/K scatter bf16 global, V -> Vs LDS ----
    for (int p = w; p < 36; p += 4) {
        int rt = p % 2, tt = p / 2;
        int sec = tt / 6, nn = tt % 6;
        int n0 = sec*128 + nn*16;
        f32x4 acc = (f32x4){0.f,0.f,0.f,0.f};
        #pragma unroll
        for (int ks = 0; ks < 3; ks++) {
            s16x8 a = *(const s16x8*)&MPBs[(rt*16+qrow)*104 + ks*32 + grp*8];
            s16x8 b = *(const s16x8*)&wu[SBQKV + (size_t)(n0+qrow)*96 + ks*32 + grp*8];
            acc = __builtin_amdgcn_mfma_f32_16x16x32_bf16(a, b, acc, 0, 0, 0);
        }
        int o = nn*16 + qrow;
        if (o < 88) {
            int h = o / 22, d = o % 22;
            #pragma unroll
            for (int j = 0; j < 4; j++) {
                int i = rt*16 + rj + j;
                int g = p0 + i, b_ = g >> 11, ss = g & 2047;
                if (sec == 0)
                    wu[SQB + ((size_t)(b_*4+h)*2048 + ss)*32 + d] = f2bf(acc[j]);
                else if (sec == 1)
                    wu[SKB + ((size_t)(b_*4+h)*2048 + ss)*32 + d] = f2bf(acc[j]);
                else
                    Vs[i*96 + o] = f2bf(acc[j]);
            }
        }
    }
    // Q/K pad zeros d=22..31 (32 rows x 4h x 10d x 2 arrays = 2560)
    for (int e = tid; e < 2560; e += 256) {
        int pp = e & 31, r = e >> 5;
        int arr = r / 40, rr = r % 40, h = rr / 10, dpad = 22 + rr % 10;
        int g = p0 + pp, b_ = g >> 11, ss = g & 2047;
        wu[(arr ? SKB : SQB) + ((size_t)(b_*4+h)*2048 + ss)*32 + dpad] = 0;
    }
    __syncthreads();

    // ---- DWT(Vs) -> CDT bf16 + cA -> XOB ----
    int b_ = p0 >> 11, sbase = p0 & 2047;
    #pragma unroll
    for (int it = 0; it < 7; it++) {
        int idx = it*256 + tid;             // 1792 = 32 pos x 56 (h,jj)
        int pp = idx & 31, hjj = idx >> 5;
        int h = hjj / 14, jj = hjj - h*14;
        const u16* v = &Vs[pp*96 + h*22];
        float ca = 0.f, cd = 0.f;
        #pragma unroll
        for (int t = 0; t < 8; t++) {
            int q = 1 + 2*jj + t;
            int oi = q < 7 ? 6 - q : (q < 29 ? q - 7 : 50 - q);
            float vv = bf2f(v[oi]);
            ca = fmaf(vv, c_dlo[7-t], ca);
            cd = fmaf(vv, c_dhi[7-t], cd);
        }
        int s = sbase + pp;
        wu[SCDT + ((size_t)((b_*4+h)*16 + jj))*2048 + s] = f2bf(cd);
        int hs = h*2048 + s, s2 = hs >> 2, qd = hs & 3;
        wu[SXOB + ((size_t)b_*2048 + s2)*112 + 56 + qd*14 + jj] = f2bf(ca);
    }
    {   // CDT pad rows d=14,15
        int pp = tid & 31, t = tid >> 5;
        int h = t >> 1, dd = 14 + (t & 1);
        wu[SCDT + ((size_t)((b_*4+h)*16 + dd))*2048 + sbase + pp] = 0;
    }
}

// ------- bf16 MFMA GEMM (final projection only) ---------------------------
struct GemmChunks {
    int soff[5];
    int stride[5];
    int cols[5];
};

template<int NCH>
__global__ __launch_bounds__(256) void gemmk(GemmChunks ch,
    const u16* __restrict__ wsrc, const u16* __restrict__ Bw,
    const float* __restrict__ bias, const float* __restrict__ resid,
    float* __restrict__ outf, int outStride, int N)
{
    constexpr int BSTR = NCH * 96 + 8;
    constexpr int KTOT = NCH * 96;
    __shared__ u16 As[64 * NCH * 104];
    __shared__ u16 Bs[64 * BSTR];
    int tid = threadIdx.x;
    int lane = tid & 63, w = tid >> 6, wr = w >> 1, wc = w & 1;
    int p0 = blockIdx.x * 64;
    int nb = blockIdx.y;

    for (int e = tid; e < NCH * 768; e += 256) {
        int c = e / 768, rem = e - c*768;
        int r = rem / 12, seg = rem % 12;
        int row = p0 + r;
        int4 v = {0,0,0,0};
        if (seg*8 < ch.cols[c])
            v = *(const int4*)&wsrc[(size_t)ch.soff[c] + (size_t)row*ch.stride[c] + seg*8];
        *(int4*)&As[c*6656 + r*104 + seg*8] = v;
    }
    for (int e = tid; e < 64 * NCH * 12; e += 256) {
        int n = e / (NCH*12), seg = e % (NCH*12);
        *(int4*)&Bs[n*BSTR + seg*8] =
            *(const int4*)&Bw[((size_t)(nb*64 + n))*KTOT + seg*8];
    }
    __syncthreads();

    f32x4 acc[2][2];
    #pragma unroll
    for (int a = 0; a < 2; a++)
        #pragma unroll
        for (int b = 0; b < 2; b++) acc[a][b] = (f32x4){0.f,0.f,0.f,0.f};

    int ar0 = (wr*32 + (lane&15))*104 + (lane>>4)*8;
    int br0 = (wc*32 + (lane&15))*BSTR + (lane>>4)*8;

    #pragma unroll
    for (int c = 0; c < NCH; c++) {
        int abase = c*6656 + ar0;
        int bbase = br0 + c*96;
        #pragma unroll
        for (int ks = 0; ks < 3; ks++) {
            s16x8 a0 = *(const s16x8*)&As[abase + ks*32];
            s16x8 a1 = *(const s16x8*)&As[abase + 16*104 + ks*32];
            s16x8 b0 = *(const s16x8*)&Bs[bbase + ks*32];
            s16x8 b1 = *(const s16x8*)&Bs[bbase + 16*BSTR + ks*32];
            acc[0][0] = __builtin_amdgcn_mfma_f32_16x16x32_bf16(a0, b0, acc[0][0], 0, 0, 0);
            acc[0][1] = __builtin_amdgcn_mfma_f32_16x16x32_bf16(a0, b1, acc[0][1], 0, 0, 0);
            acc[1][0] = __builtin_amdgcn_mfma_f32_16x16x32_bf16(a1, b0, acc[1][0], 0, 0, 0);
            acc[1][1] = __builtin_amdgcn_mfma_f32_16x16x32_bf16(a1, b1, acc[1][1], 0, 0, 0);
        }
    }

    int rbase = p0 + wr*32 + (lane>>4)*4;
    int cbase = nb*64 + wc*32 + (lane&15);
    #pragma unroll
    for (int fn = 0; fn < 2; fn++) {
        int col = cbase + fn*16;
        if (col < N) {
            float bb = bias[col];
            #pragma unroll
            for (int fm = 0; fm < 2; fm++)
                #pragma unroll
                for (int j = 0; j < 4; j++) {
                    int row = rbase + fm*16 + j;
                    float v = acc[fm][fn][j] + bb + resid[(size_t)row*outStride + col];
                    outf[(size_t)row*outStride + col] = v;
                }
        }
    }
}

// ---- MFMA flash attention, 2-way split-K + defer-max + reg prefetch ------
__global__ __launch_bounds__(512, 4) void attnk(float* __restrict__ ws)
{
    const u16* wu = (const u16*)ws;
    u16* wua = (u16*)ws;
    __shared__ __align__(16) u16 Kt[2*64*40];
    __shared__ __align__(16) u16 CDt[2*16*72];
    __shared__ __align__(16) u16 Pb[8][16*72];
    int tid = threadIdx.x, lane = tid & 63, w = tid >> 6;
    int bh = blockIdx.y;
    int qsub = w & 3, half = w >> 2;
    int q0 = blockIdx.x * 64 + qsub * 16;
    int qrow = lane & 15, grp = lane >> 4;

    s16x8 qf = *(const s16x8*)&wu[SQB + ((size_t)bh*2048 + q0 + qrow)*32 + grp*8];
    const u16* Kbase = wu + SKB + (size_t)bh*2048*32;
    const u16* Cbase = wu + SCDT + (size_t)bh*16*2048;
    const u16* Kh = &Kt[half*2560];
    const u16* Ch = &CDt[half*1152];

    int khh = tid >> 8, krr = (tid >> 2) & 63, kseg = tid & 3;
    int chh = tid >> 7, cdd = (tid >> 3) & 15, cseg = tid & 7;

    f32x4 o = (f32x4){0.f,0.f,0.f,0.f};
    float m = -1e30f, l = 0.f;

    int4 kreg = *(const int4*)&Kbase[(size_t)(khh*1024 + krr)*32 + kseg*8];
    int4 creg = {0,0,0,0};
    if (tid < 256)
        creg = *(const int4*)&Cbase[(size_t)cdd*2048 + chh*1024 + cseg*8];

    for (int kt = 0; kt < 16; kt++) {
        __syncthreads();
        *(int4*)&Kt[khh*2560 + krr*40 + kseg*8] = kreg;
        if (tid < 256) *(int4*)&CDt[chh*1152 + cdd*72 + cseg*8] = creg;
        __syncthreads();
        if (kt < 15) {
            kreg = *(const int4*)&Kbase[(size_t)(khh*1024 + (kt+1)*64 + krr)*32 + kseg*8];
            if (tid < 256)
                creg = *(const int4*)&Cbase[(size_t)cdd*2048 + chh*1024 + (kt+1)*64 + cseg*8];
        }

        f32x4 s4[4];
        #pragma unroll
        for (int sub = 0; sub < 4; sub++) {
            s16x8 kf = *(const s16x8*)&Kh[(sub*16 + qrow)*40 + grp*8];
            s4[sub] = __builtin_amdgcn_mfma_f32_16x16x32_bf16(kf, qf,
                        (f32x4){0.f,0.f,0.f,0.f}, 0, 0, 0);
        }
        float sv[16];
        #pragma unroll
        for (int sub = 0; sub < 4; sub++)
            #pragma unroll
            for (int j = 0; j < 4; j++) sv[sub*4+j] = s4[sub][j];

        float mx[8];
        #pragma unroll
        for (int i = 0; i < 8; i++) mx[i] = fmaxf(sv[i], sv[i+8]);
        #pragma unroll
        for (int i = 0; i < 4; i++) mx[i] = fmaxf(mx[i], mx[i+4]);
        float tm = fmaxf(fmaxf(mx[0], mx[1]), fmaxf(mx[2], mx[3]));
        tm = fmaxf(tm, __shfl_xor(tm, 16));
        tm = fmaxf(tm, __shfl_xor(tm, 32));

        if (!__all(tm <= m + 8.f)) {
            float mn = fmaxf(m, tm);
            float corr = __expf(m - mn);
            m = mn; l *= corr;
            #pragma unroll
            for (int j = 0; j < 4; j++) o[j] *= __shfl(corr, grp*4 + j);
        }

        float pv[16];
        #pragma unroll
        for (int i = 0; i < 16; i++) pv[i] = __expf(sv[i] - m);
        float sm[8];
        #pragma unroll
        for (int i = 0; i < 8; i++) sm[i] = pv[i] + pv[i+8];
        #pragma unroll
        for (int i = 0; i < 4; i++) sm[i] += sm[i+4];
        float ls = (sm[0] + sm[1]) + (sm[2] + sm[3]);
        ls += __shfl_xor(ls, 16);
        ls += __shfl_xor(ls, 32);
        l += ls;

        {
            uint* pb32 = (uint*)Pb[w];
            #pragma unroll
            for (int sub = 0; sub < 4; sub++) {
                uint u01 = (uint)f2bf(pv[sub*4+0]) | ((uint)f2bf(pv[sub*4+1]) << 16);
                uint u23 = (uint)f2bf(pv[sub*4+2]) | ((uint)f2bf(pv[sub*4+3]) << 16);
                int sa = qrow*72 + sub*16 + grp*4;
                *(uint2*)&pb32[sa >> 1] = make_uint2(u01, u23);
            }
        }
        #pragma unroll
        for (int ks = 0; ks < 2; ks++) {
            s16x8 pa = *(const s16x8*)&Pb[w][qrow*72 + ks*32 + grp*8];
            s16x8 cf = *(const s16x8*)&Ch[qrow*72 + ks*32 + grp*8];
            o = __builtin_amdgcn_mfma_f32_16x16x32_bf16(pa, cf, o, 0, 0, 0);
        }
    }

    __syncthreads();
    float* part = (float*)Kt;
    if (lane < 16) { part[(w*16+lane)*18 + 0] = m; part[(w*16+lane)*18 + 1] = l; }
    #pragma unroll
    for (int j = 0; j < 4; j++) part[(w*16 + grp*4 + j)*18 + 2 + qrow] = o[j];
    __syncthreads();
    if (w < 4) {
        int q = qrow;
        const float* pa = &part[(w*16 + q)*18];
        const float* pb = &part[((w+4)*16 + q)*18];
        float m0 = pa[0], l0 = pa[1], m1 = pb[0], l1 = pb[1];
        float M = fmaxf(m0, m1);
        float e0 = __expf(m0 - M), e1 = __expf(m1 - M);
        float inv = 1.f / (l0*e0 + l1*e1);
        int b = bh >> 2, h = bh & 3;
        int s = blockIdx.x * 64 + w * 16 + q;
        #pragma unroll
        for (int dd = 0; dd < 4; dd++) {
            int d = grp*4 + dd;
            if (d < 14) {
                float val = (pa[2+d]*e0 + pb[2+d]*e1) * inv;
                wua[SXOB + ((size_t)b*2048 + s)*112 + h*14 + d] = f2bf(fmaxf(val, 0.f));
            }
        }
    }
}

extern "C" void kernel_launch(void* const* d_in, const int* in_sizes, int n_in,
                              void* d_out, int out_size, void* d_ws, size_t ws_size,
                              hipStream_t stream) {
    const float* x    = (const float*)d_in[0];
    const float* w1   = (const float*)d_in[1];
    const float* w2a  = (const float*)d_in[2];
    const float* w2b  = (const float*)d_in[3];
    const float* w3a  = (const float*)d_in[4];
    const float* w3b  = (const float*)d_in[5];
    const float* w3c  = (const float*)d_in[6];
    const float* g1   = (const float*)d_in[7];
    const float* g2a  = (const float*)d_in[8];
    const float* g2b  = (const float*)d_in[9];
    const float* g3a  = (const float*)d_in[10];
    const float* g3b  = (const float*)d_in[11];
    const float* g3c  = (const float*)d_in[12];
    const float* b1   = (const float*)d_in[13];
    const float* b2a  = (const float*)d_in[14];
    const float* b2b  = (const float*)d_in[15];
    const float* b3a  = (const float*)d_in[16];
    const float* b3b  = (const float*)d_in[17];
    const float* b3c  = (const float*)d_in[18];
    const float* Wmp  = (const float*)d_in[19];
    const float* bmp  = (const float*)d_in[20];
    const float* Wq   = (const float*)d_in[21];
    const float* Wk   = (const float*)d_in[22];
    const float* Wv   = (const float*)d_in[23];
    const float* Wout = (const float*)d_in[24];
    const float* bout = (const float*)d_in[25];
    float* ws = (float*)d_ws;
    float* out = (float*)d_out;
    u16* wu = (u16*)d_ws;

    prepk<<<3850, 256, 0, stream>>>(x, w1, w2a, w2b, w3a, w3b, w3c,
                                    g1, g2a, g2b, g3a, g3b, g3c,
                                    b1, b2a, b3a, Wmp, Wq, Wk, Wv, Wout, ws);
    megak<<<256, 256, 0, stream>>>(x, b2b, b3b, b3c, bmp, ws);
    attnk<<<dim3(32, 16), 512, 0, stream>>>(ws);
    {   // final: XOb @ WBOUT + bout + MP -> out
        GemmChunks c{};
        c.soff[0]=SXOB;    c.stride[0]=112; c.cols[0]=96;
        c.soff[1]=SXOB+96; c.stride[1]=112; c.cols[1]=16;
        gemmk<2><<<dim3(128,2), 256, 0, stream>>>(c, wu, wu+SBOUT,
            bout, ws+OFF_MP, out, 88, 88);
    }
}

// Round 13
// 173.796 us; speedup vs baseline: 1.1792x; 1.0880x over previous
//
#include <hip/hip_runtime.h>

#define BN_INV  0.99999500003749981f
#define QSCALE  0.21320071635561041f   // 22^-0.5

typedef unsigned int uint;
typedef unsigned short u16;
typedef __attribute__((ext_vector_type(8))) short s16x8;
typedef __attribute__((ext_vector_type(4))) float f32x4;

// ---- ws layout ----
// float offsets:
#define OFF_BCAT 0         // 264
#define OFF_MP   721408    // 8192*88 fp32 (final residual)
// short offsets:
#define SW0    2884608
#define SB1    (SW0)            // 320 x 96
#define SB2B   (SW0+30720)      // 128 x 288
#define SB3B   (SW0+67584)      // 128 x 288
#define SB3C   (SW0+104448)     // 128 x 480
#define SBMP   (SW0+165888)     // 128 x 288
#define SBQKV  (SW0+202752)     // 384 x 96
#define SBOUT  (SW0+239616)     // 128 x 192
#define SXB    3148800     // xb   [8192][88]
#define SQB    3869696     // Qb  [16][2048][32]
#define SKB    4918272     // Kb  [16][2048][32]
#define SCDT   5966848     // CDT [16][16][2048]
#define SXOB   6753280     // XOb [8192][112]

__constant__ float c_dlo[8] = {-0.010597401784997278f, 0.032883011666982945f,
    0.030841381835986965f, -0.18703481171888114f, -0.02798376941698385f,
    0.6308807679295904f, 0.7148465705525415f, 0.23037781330885523f};
__constant__ float c_dhi[8] = {-0.23037781330885523f, 0.7148465705525415f,
    -0.6308807679295904f, -0.02798376941698385f, 0.18703481171888114f,
    0.030841381835986965f, -0.032883011666982945f, -0.010597401784997278f};

__device__ __forceinline__ u16 f2bf(float f) {
    uint u = __float_as_uint(f);
    uint r = u + 0x7fffu + ((u >> 16) & 1u);
    return (u16)(r >> 16);
}
__device__ __forceinline__ float bf2f(u16 u) {
    return __uint_as_float((uint)u << 16);
}

// ---------------- weight prep + x->bf16 ----------------------------------
__global__ __launch_bounds__(256) void prepk(
    const float* __restrict__ x,
    const float* __restrict__ w1, const float* __restrict__ w2a, const float* __restrict__ w2b,
    const float* __restrict__ w3a, const float* __restrict__ w3b, const float* __restrict__ w3c,
    const float* __restrict__ g1, const float* __restrict__ g2a, const float* __restrict__ g2b,
    const float* __restrict__ g3a, const float* __restrict__ g3b, const float* __restrict__ g3c,
    const float* __restrict__ b1, const float* __restrict__ b2a, const float* __restrict__ b3a,
    const float* __restrict__ Wmp, const float* __restrict__ Wq, const float* __restrict__ Wk,
    const float* __restrict__ Wv, const float* __restrict__ Wout, float* __restrict__ ws)
{
    u16* wu = (u16*)ws;
    int r = blockIdx.x * 256 + threadIdx.x;
    if (r < 264) {
        ws[OFF_BCAT + r] = (r < 88) ? b1[r] : (r < 176 ? b2a[r-88] : b3a[r-176]);
        return;
    }
    r -= 264;
    if (r < 320*96) {                       // WB1: cat(w1,w2a,w3a) folded
        int n = r / 96, kk = r % 96; float v = 0.f;
        if (kk < 88 && n < 264) {
            if (n < 88)       v = w1 [n*88+kk]       * g1 [n];
            else if (n < 176) v = w2a[(n-88)*88+kk]  * g2a[n-88];
            else              v = w3a[(n-176)*88+kk] * g3a[n-176];
            v *= BN_INV;
        }
        wu[SB1 + r] = f2bf(v); return;
    }
    r -= 320*96;
    if (r < 128*288) {                      // WB2B
        int n = r / 288, kk = r % 288, t = kk/96, i = kk%96; float v = 0.f;
        if (n < 88 && i < 88) v = w2b[n*264 + i*3 + t] * g2b[n] * BN_INV;
        wu[SB2B + r] = f2bf(v); return;
    }
    r -= 128*288;
    if (r < 128*288) {                      // WB3B
        int n = r / 288, kk = r % 288, t = kk/96, i = kk%96; float v = 0.f;
        if (n < 88 && i < 88) v = w3b[n*264 + i*3 + t] * g3b[n] * BN_INV;
        wu[SB3B + r] = f2bf(v); return;
    }
    r -= 128*288;
    if (r < 128*480) {                      // WB3C
        int n = r / 480, kk = r % 480, t = kk/96, i = kk%96; float v = 0.f;
        if (n < 88 && i < 88) v = w3c[n*440 + i*5 + t] * g3c[n] * BN_INV;
        wu[SB3C + r] = f2bf(v); return;
    }
    r -= 128*480;
    if (r < 128*288) {                      // WBMP
        int n = r / 288, kk = r % 288, c = kk/96, i = kk%96; float v = 0.f;
        if (n < 88 && i < 88) v = Wmp[n*264 + c*88 + i];
        wu[SBMP + r] = f2bf(v); return;
    }
    r -= 128*288;
    if (r < 384*96) {                       // WBQKV (q-scale folded)
        int n = r / 96, kk = r % 96, sec = n / 128, o = n % 128; float v = 0.f;
        if (o < 88 && kk < 88) {
            if (sec == 0)      v = Wq[o*88+kk] * QSCALE;
            else if (sec == 1) v = Wk[o*88+kk];
            else               v = Wv[o*88+kk];
        }
        wu[SBQKV + r] = f2bf(v); return;
    }
    r -= 384*96;
    if (r < 128*192) {                      // WBOUT
        int n = r / 192, kk = r % 192; float v = 0.f;
        if (n < 88 && kk < 112) v = Wout[n*112 + kk];
        wu[SBOUT + r] = f2bf(v); return;
    }
    r -= 128*192;
    if (r < 8192*88) {                      // xb
        wu[SXB + r] = f2bf(x[r]); return;
    }
}

// ---- MEGA kernel: conv1 -> conv3a/b -> conv5 -> mp -> qkv -> dwt ---------
// 256 blocks x 32 rows, 512 thr = 8 waves (2 waves/SIMD).
// B fragments read directly from L2-resident weight tables.
__global__ __launch_bounds__(512) void megak(const float* __restrict__ x,
    const float* __restrict__ b2b, const float* __restrict__ b3b,
    const float* __restrict__ b3c, const float* __restrict__ bmp,
    float* __restrict__ ws)
{
    u16* wu = (u16*)ws;
    __shared__ __align__(16) u16 XBs[48*104];    // xb rows p0-3..p0+44; X2s overlay
    __shared__ __align__(16) u16 TC [52*280];    // conv1 out rows p0-3+i (pad 280: 2-way)
    __shared__ __align__(16) u16 T3Bs[36*104];   // rows p0-2+i
    __shared__ __align__(16) u16 X3s[32*104];
    __shared__ __align__(16) u16 MPBs[32*104];
    __shared__ __align__(16) u16 Vs[32*100];     // pad 100: 2-way
    u16* X2s = XBs;                              // overlay (XB dead after conv1)

    int tid = threadIdx.x, lane = tid & 63, w = tid >> 6;
    int p0 = blockIdx.x * 32;
    int bs = p0 & ~2047, be = bs + 2048;
    int qrow = lane & 15, grp = lane >> 4;
    int rj = grp * 4;

    // ---- stage xb rows p0-3..p0+44 (48 rows x 96 cols, pad zero) ----
    for (int e = tid; e < 576; e += 512) {
        int r = e / 12, seg = e % 12;
        int grow = p0 - 3 + r;
        int4 v = {0,0,0,0};
        if (seg < 11 && grow >= 0 && grow < 8192)
            v = *(const int4*)&wu[SXB + (size_t)grow*88 + seg*8];
        *(int4*)&XBs[r*104 + seg*8] = v;
    }
    __syncthreads();

    // ---- conv1: TC rows 0..47 (global p0-3+r), cols 0..271 ----
    for (int p = w; p < 51; p += 8) {
        int rt = p % 3, ct = p / 3;
        f32x4 acc = (f32x4){0.f,0.f,0.f,0.f};
        #pragma unroll
        for (int ks = 0; ks < 3; ks++) {
            s16x8 a = *(const s16x8*)&XBs[(rt*16+qrow)*104 + ks*32 + grp*8];
            s16x8 b = *(const s16x8*)&wu[SB1 + (size_t)(ct*16+qrow)*96 + ks*32 + grp*8];
            acc = __builtin_amdgcn_mfma_f32_16x16x32_bf16(a, b, acc, 0, 0, 0);
        }
        int col = ct*16 + qrow;
        float bb = (col < 264) ? ws[OFF_BCAT + col] : 0.f;
        #pragma unroll
        for (int j = 0; j < 4; j++) {
            int r = rt*16 + rj + j;
            int grow = p0 - 3 + r;
            float v = fmaxf(acc[j] + bb, 0.f);
            TC[r*280 + col] = (grow >= bs && grow < be) ? f2bf(v) : (u16)0;
        }
    }
    __syncthreads();

    // ---- conv3a (X2s rows 0..31) + conv3b (T3Bs rows 0..35) ----
    for (int p = w; p < 30; p += 8) {
        if (p < 12) {
            int rt = p % 2, ct = p / 2;
            f32x4 acc = (f32x4){0.f,0.f,0.f,0.f};
            #pragma unroll
            for (int t = 0; t < 3; t++)
                #pragma unroll
                for (int ks = 0; ks < 3; ks++) {
                    s16x8 a = *(const s16x8*)&TC[((2+t) + rt*16+qrow)*280 + 88 + ks*32 + grp*8];
                    s16x8 b = *(const s16x8*)&wu[SB2B + (size_t)(ct*16+qrow)*288 + t*96 + ks*32 + grp*8];
                    acc = __builtin_amdgcn_mfma_f32_16x16x32_bf16(a, b, acc, 0, 0, 0);
                }
            int col = ct*16 + qrow;
            float bb = (col < 88) ? b2b[col] : 0.f;
            #pragma unroll
            for (int j = 0; j < 4; j++) {
                int i = rt*16 + rj + j;
                X2s[i*104 + col] = f2bf(fmaxf(acc[j] + bb, 0.f));
            }
        } else {
            int pp = p - 12, rt = pp % 3, ct = pp / 3;
            f32x4 acc = (f32x4){0.f,0.f,0.f,0.f};
            #pragma unroll
            for (int t = 0; t < 3; t++)
                #pragma unroll
                for (int ks = 0; ks < 3; ks++) {
                    s16x8 a = *(const s16x8*)&TC[(rt*16+qrow + t)*280 + 176 + ks*32 + grp*8];
                    s16x8 b = *(const s16x8*)&wu[SB3B + (size_t)(ct*16+qrow)*288 + t*96 + ks*32 + grp*8];
                    acc = __builtin_amdgcn_mfma_f32_16x16x32_bf16(a, b, acc, 0, 0, 0);
                }
            int col = ct*16 + qrow;
            float bb = (col < 88) ? b3b[col] : 0.f;
            #pragma unroll
            for (int j = 0; j < 4; j++) {
                int i = rt*16 + rj + j;
                if (i < 36) {
                    int grow = p0 - 2 + i;
                    float v = fmaxf(acc[j] + bb, 0.f);
                    T3Bs[i*104 + col] = (grow >= bs && grow < be) ? f2bf(v) : (u16)0;
                }
            }
        }
    }
    __syncthreads();

    // ---- conv5: X3s rows 0..31 ----
    for (int p = w; p < 12; p += 8) {
        int rt = p % 2, ct = p / 2;
        f32x4 acc = (f32x4){0.f,0.f,0.f,0.f};
        #pragma unroll
        for (int t = 0; t < 5; t++)
            #pragma unroll
            for (int ks = 0; ks < 3; ks++) {
                s16x8 a = *(const s16x8*)&T3Bs[(rt*16+qrow + t)*104 + ks*32 + grp*8];
                s16x8 b = *(const s16x8*)&wu[SB3C + (size_t)(ct*16+qrow)*480 + t*96 + ks*32 + grp*8];
                acc = __builtin_amdgcn_mfma_f32_16x16x32_bf16(a, b, acc, 0, 0, 0);
            }
        int col = ct*16 + qrow;
        float bb = (col < 88) ? b3c[col] : 0.f;
        #pragma unroll
        for (int j = 0; j < 4; j++) {
            int i = rt*16 + rj + j;
            X3s[i*104 + col] = f2bf(fmaxf(acc[j] + bb, 0.f));
        }
    }
    __syncthreads();

    // ---- mp: MPBs bf16 + MP fp32 (resid for final) ----
    for (int p = w; p < 12; p += 8) {
        int rt = p % 2, ct = p / 2;
        f32x4 acc = (f32x4){0.f,0.f,0.f,0.f};
        #pragma unroll
        for (int ks = 0; ks < 3; ks++) {
            s16x8 a = *(const s16x8*)&TC[(3 + rt*16+qrow)*280 + ks*32 + grp*8];
            s16x8 b = *(const s16x8*)&wu[SBMP + (size_t)(ct*16+qrow)*288 + ks*32 + grp*8];
            acc = __builtin_amdgcn_mfma_f32_16x16x32_bf16(a, b, acc, 0, 0, 0);
        }
        #pragma unroll
        for (int ks = 0; ks < 3; ks++) {
            s16x8 a = *(const s16x8*)&X2s[(rt*16+qrow)*104 + ks*32 + grp*8];
            s16x8 b = *(const s16x8*)&wu[SBMP + (size_t)(ct*16+qrow)*288 + 96 + ks*32 + grp*8];
            acc = __builtin_amdgcn_mfma_f32_16x16x32_bf16(a, b, acc, 0, 0, 0);
        }
        #pragma unroll
        for (int ks = 0; ks < 3; ks++) {
            s16x8 a = *(const s16x8*)&X3s[(rt*16+qrow)*104 + ks*32 + grp*8];
            s16x8 b = *(const s16x8*)&wu[SBMP + (size_t)(ct*16+qrow)*288 + 192 + ks*32 + grp*8];
            acc = __builtin_amdgcn_mfma_f32_16x16x32_bf16(a, b, acc, 0, 0, 0);
        }
        int col = ct*16 + qrow;
        float bb = (col < 88) ? bmp[col] : 0.f;
        #pragma unroll
        for (int j = 0; j < 4; j++) {
            int i = rt*16 + rj + j;
            float v = acc[j] + bb;
            if (col < 88) {
                v += x[(size_t)(p0+i)*88 + col];
                ws[OFF_MP + (size_t)(p0+i)*88 + col] = v;
            } else v = 0.f;
            MPBs[i*104 + col] = f2bf(v);
        }
    }
    __syncthreads();

    // ---- qkv: Q/K scatter bf16 global, V -> Vs LDS ----
    for (int p = w; p < 36; p += 8) {
        int rt = p % 2, tt = p / 2;
        int sec = tt / 6, nn = tt % 6;
        int n0 = sec*128 + nn*16;
        f32x4 acc = (f32x4){0.f,0.f,0.f,0.f};
        #pragma unroll
        for (int ks = 0; ks < 3; ks++) {
            s16x8 a = *(const s16x8*)&MPBs[(rt*16+qrow)*104 + ks*32 + grp*8];
            s16x8 b = *(const s16x8*)&wu[SBQKV + (size_t)(n0+qrow)*96 + ks*32 + grp*8];
            acc = __builtin_amdgcn_mfma_f32_16x16x32_bf16(a, b, acc, 0, 0, 0);
        }
        int o = nn*16 + qrow;
        if (o < 88) {
            int h = o / 22, d = o % 22;
            #pragma unroll
            for (int j = 0; j < 4; j++) {
                int i = rt*16 + rj + j;
                int g = p0 + i, b_ = g >> 11, ss = g & 2047;
                if (sec == 0)
                    wu[SQB + ((size_t)(b_*4+h)*2048 + ss)*32 + d] = f2bf(acc[j]);
                else if (sec == 1)
                    wu[SKB + ((size_t)(b_*4+h)*2048 + ss)*32 + d] = f2bf(acc[j]);
                else
                    Vs[i*100 + o] = f2bf(acc[j]);
            }
        }
    }
    // Q/K pad zeros d=22..31 (32 rows x 4h x 10d x 2 arrays = 2560)
    for (int e = tid; e < 2560; e += 512) {
        int pp = e & 31, r = e >> 5;
        int arr = r / 40, rr = r % 40, h = rr / 10, dpad = 22 + rr % 10;
        int g = p0 + pp, b_ = g >> 11, ss = g & 2047;
        wu[(arr ? SKB : SQB) + ((size_t)(b_*4+h)*2048 + ss)*32 + dpad] = 0;
    }
    __syncthreads();

    // ---- DWT(Vs) -> CDT bf16 + cA -> XOB ----
    int b_ = p0 >> 11, sbase = p0 & 2047;
    for (int idx = tid; idx < 1792; idx += 512) {   // 32 pos x 56 (h,jj)
        int pp = idx & 31, hjj = idx >> 5;
        int h = hjj / 14, jj = hjj - h*14;
        const u16* v = &Vs[pp*100 + h*22];
        float ca = 0.f, cd = 0.f;
        #pragma unroll
        for (int t = 0; t < 8; t++) {
            int q = 1 + 2*jj + t;
            int oi = q < 7 ? 6 - q : (q < 29 ? q - 7 : 50 - q);
            float vv = bf2f(v[oi]);
            ca = fmaf(vv, c_dlo[7-t], ca);
            cd = fmaf(vv, c_dhi[7-t], cd);
        }
        int s = sbase + pp;
        wu[SCDT + ((size_t)((b_*4+h)*16 + jj))*2048 + s] = f2bf(cd);
        int hs = h*2048 + s, s2 = hs >> 2, qd = hs & 3;
        wu[SXOB + ((size_t)b_*2048 + s2)*112 + 56 + qd*14 + jj] = f2bf(ca);
    }
    if (tid < 256) {   // CDT pad rows d=14,15
        int pp = tid & 31, t = tid >> 5;
        int h = t >> 1, dd = 14 + (t & 1);
        wu[SCDT + ((size_t)((b_*4+h)*16 + dd))*2048 + sbase + pp] = 0;
    }
}

// ------- bf16 MFMA GEMM (final projection only) ---------------------------
struct GemmChunks {
    int soff[5];
    int stride[5];
    int cols[5];
};

template<int NCH>
__global__ __launch_bounds__(256) void gemmk(GemmChunks ch,
    const u16* __restrict__ wsrc, const u16* __restrict__ Bw,
    const float* __restrict__ bias, const float* __restrict__ resid,
    float* __restrict__ outf, int outStride, int N)
{
    constexpr int BSTR = NCH * 96 + 8;
    constexpr int KTOT = NCH * 96;
    __shared__ u16 As[64 * NCH * 104];
    __shared__ u16 Bs[64 * BSTR];
    int tid = threadIdx.x;
    int lane = tid & 63, w = tid >> 6, wr = w >> 1, wc = w & 1;
    int p0 = blockIdx.x * 64;
    int nb = blockIdx.y;

    for (int e = tid; e < NCH * 768; e += 256) {
        int c = e / 768, rem = e - c*768;
        int r = rem / 12, seg = rem % 12;
        int row = p0 + r;
        int4 v = {0,0,0,0};
        if (seg*8 < ch.cols[c])
            v = *(const int4*)&wsrc[(size_t)ch.soff[c] + (size_t)row*ch.stride[c] + seg*8];
        *(int4*)&As[c*6656 + r*104 + seg*8] = v;
    }
    for (int e = tid; e < 64 * NCH * 12; e += 256) {
        int n = e / (NCH*12), seg = e % (NCH*12);
        *(int4*)&Bs[n*BSTR + seg*8] =
            *(const int4*)&Bw[((size_t)(nb*64 + n))*KTOT + seg*8];
    }
    __syncthreads();

    f32x4 acc[2][2];
    #pragma unroll
    for (int a = 0; a < 2; a++)
        #pragma unroll
        for (int b = 0; b < 2; b++) acc[a][b] = (f32x4){0.f,0.f,0.f,0.f};

    int ar0 = (wr*32 + (lane&15))*104 + (lane>>4)*8;
    int br0 = (wc*32 + (lane&15))*BSTR + (lane>>4)*8;

    #pragma unroll
    for (int c = 0; c < NCH; c++) {
        int abase = c*6656 + ar0;
        int bbase = br0 + c*96;
        #pragma unroll
        for (int ks = 0; ks < 3; ks++) {
            s16x8 a0 = *(const s16x8*)&As[abase + ks*32];
            s16x8 a1 = *(const s16x8*)&As[abase + 16*104 + ks*32];
            s16x8 b0 = *(const s16x8*)&Bs[bbase + ks*32];
            s16x8 b1 = *(const s16x8*)&Bs[bbase + 16*BSTR + ks*32];
            acc[0][0] = __builtin_amdgcn_mfma_f32_16x16x32_bf16(a0, b0, acc[0][0], 0, 0, 0);
            acc[0][1] = __builtin_amdgcn_mfma_f32_16x16x32_bf16(a0, b1, acc[0][1], 0, 0, 0);
            acc[1][0] = __builtin_amdgcn_mfma_f32_16x16x32_bf16(a1, b0, acc[1][0], 0, 0, 0);
            acc[1][1] = __builtin_amdgcn_mfma_f32_16x16x32_bf16(a1, b1, acc[1][1], 0, 0, 0);
        }
    }

    int rbase = p0 + wr*32 + (lane>>4)*4;
    int cbase = nb*64 + wc*32 + (lane&15);
    #pragma unroll
    for (int fn = 0; fn < 2; fn++) {
        int col = cbase + fn*16;
        if (col < N) {
            float bb = bias[col];
            #pragma unroll
            for (int fm = 0; fm < 2; fm++)
                #pragma unroll
                for (int j = 0; j < 4; j++) {
                    int row = rbase + fm*16 + j;
                    float v = acc[fm][fn][j] + bb + resid[(size_t)row*outStride + col];
                    outf[(size_t)row*outStride + col] = v;
                }
        }
    }
}

// ---- MFMA flash attention, 2-way split-K + defer-max + reg prefetch ------
__global__ __launch_bounds__(512, 4) void attnk(float* __restrict__ ws)
{
    const u16* wu = (const u16*)ws;
    u16* wua = (u16*)ws;
    __shared__ __align__(16) u16 Kt[2*64*40];
    __shared__ __align__(16) u16 CDt[2*16*72];
    __shared__ __align__(16) u16 Pb[8][16*72];
    int tid = threadIdx.x, lane = tid & 63, w = tid >> 6;
    int bh = blockIdx.y;
    int qsub = w & 3, half = w >> 2;
    int q0 = blockIdx.x * 64 + qsub * 16;
    int qrow = lane & 15, grp = lane >> 4;

    s16x8 qf = *(const s16x8*)&wu[SQB + ((size_t)bh*2048 + q0 + qrow)*32 + grp*8];
    const u16* Kbase = wu + SKB + (size_t)bh*2048*32;
    const u16* Cbase = wu + SCDT + (size_t)bh*16*2048;
    const u16* Kh = &Kt[half*2560];
    const u16* Ch = &CDt[half*1152];

    int khh = tid >> 8, krr = (tid >> 2) & 63, kseg = tid & 3;
    int chh = tid >> 7, cdd = (tid >> 3) & 15, cseg = tid & 7;

    f32x4 o = (f32x4){0.f,0.f,0.f,0.f};
    float m = -1e30f, l = 0.f;

    int4 kreg = *(const int4*)&Kbase[(size_t)(khh*1024 + krr)*32 + kseg*8];
    int4 creg = {0,0,0,0};
    if (tid < 256)
        creg = *(const int4*)&Cbase[(size_t)cdd*2048 + chh*1024 + cseg*8];

    for (int kt = 0; kt < 16; kt++) {
        __syncthreads();
        *(int4*)&Kt[khh*2560 + krr*40 + kseg*8] = kreg;
        if (tid < 256) *(int4*)&CDt[chh*1152 + cdd*72 + cseg*8] = creg;
        __syncthreads();
        if (kt < 15) {
            kreg = *(const int4*)&Kbase[(size_t)(khh*1024 + (kt+1)*64 + krr)*32 + kseg*8];
            if (tid < 256)
                creg = *(const int4*)&Cbase[(size_t)cdd*2048 + chh*1024 + (kt+1)*64 + cseg*8];
        }

        f32x4 s4[4];
        #pragma unroll
        for (int sub = 0; sub < 4; sub++) {
            s16x8 kf = *(const s16x8*)&Kh[(sub*16 + qrow)*40 + grp*8];
            s4[sub] = __builtin_amdgcn_mfma_f32_16x16x32_bf16(kf, qf,
                        (f32x4){0.f,0.f,0.f,0.f}, 0, 0, 0);
        }
        float sv[16];
        #pragma unroll
        for (int sub = 0; sub < 4; sub++)
            #pragma unroll
            for (int j = 0; j < 4; j++) sv[sub*4+j] = s4[sub][j];

        float mx[8];
        #pragma unroll
        for (int i = 0; i < 8; i++) mx[i] = fmaxf(sv[i], sv[i+8]);
        #pragma unroll
        for (int i = 0; i < 4; i++) mx[i] = fmaxf(mx[i], mx[i+4]);
        float tm = fmaxf(fmaxf(mx[0], mx[1]), fmaxf(mx[2], mx[3]));
        tm = fmaxf(tm, __shfl_xor(tm, 16));
        tm = fmaxf(tm, __shfl_xor(tm, 32));

        if (!__all(tm <= m + 8.f)) {
            float mn = fmaxf(m, tm);
            float corr = __expf(m - mn);
            m = mn; l *= corr;
            #pragma unroll
            for (int j = 0; j < 4; j++) o[j] *= __shfl(corr, grp*4 + j);
        }

        float pv[16];
        #pragma unroll
        for (int i = 0; i < 16; i++) pv[i] = __expf(sv[i] - m);
        float sm[8];
        #pragma unroll
        for (int i = 0; i < 8; i++) sm[i] = pv[i] + pv[i+8];
        #pragma unroll
        for (int i = 0; i < 4; i++) sm[i] += sm[i+4];
        float ls = (sm[0] + sm[1]) + (sm[2] + sm[3]);
        ls += __shfl_xor(ls, 16);
        ls += __shfl_xor(ls, 32);
        l += ls;

        {
            uint* pb32 = (uint*)Pb[w];
            #pragma unroll
            for (int sub = 0; sub < 4; sub++) {
                uint u01 = (uint)f2bf(pv[sub*4+0]) | ((uint)f2bf(pv[sub*4+1]) << 16);
                uint u23 = (uint)f2bf(pv[sub*4+2]) | ((uint)f2bf(pv[sub*4+3]) << 16);
                int sa = qrow*72 + sub*16 + grp*4;
                *(uint2*)&pb32[sa >> 1] = make_uint2(u01, u23);
            }
        }
        #pragma unroll
        for (int ks = 0; ks < 2; ks++) {
            s16x8 pa = *(const s16x8*)&Pb[w][qrow*72 + ks*32 + grp*8];
            s16x8 cf = *(const s16x8*)&Ch[qrow*72 + ks*32 + grp*8];
            o = __builtin_amdgcn_mfma_f32_16x16x32_bf16(pa, cf, o, 0, 0, 0);
        }
    }

    __syncthreads();
    float* part = (float*)Kt;
    if (lane < 16) { part[(w*16+lane)*18 + 0] = m; part[(w*16+lane)*18 + 1] = l; }
    #pragma unroll
    for (int j = 0; j < 4; j++) part[(w*16 + grp*4 + j)*18 + 2 + qrow] = o[j];
    __syncthreads();
    if (w < 4) {
        int q = qrow;
        const float* pa = &part[(w*16 + q)*18];
        const float* pb = &part[((w+4)*16 + q)*18];
        float m0 = pa[0], l0 = pa[1], m1 = pb[0], l1 = pb[1];
        float M = fmaxf(m0, m1);
        float e0 = __expf(m0 - M), e1 = __expf(m1 - M);
        float inv = 1.f / (l0*e0 + l1*e1);
        int b = bh >> 2, h = bh & 3;
        int s = blockIdx.x * 64 + w * 16 + q;
        #pragma unroll
        for (int dd = 0; dd < 4; dd++) {
            int d = grp*4 + dd;
            if (d < 14) {
                float val = (pa[2+d]*e0 + pb[2+d]*e1) * inv;
                wua[SXOB + ((size_t)b*2048 + s)*112 + h*14 + d] = f2bf(fmaxf(val, 0.f));
            }
        }
    }
}

extern "C" void kernel_launch(void* const* d_in, const int* in_sizes, int n_in,
                              void* d_out, int out_size, void* d_ws, size_t ws_size,
                              hipStream_t stream) {
    const float* x    = (const float*)d_in[0];
    const float* w1   = (const float*)d_in[1];
    const float* w2a  = (const float*)d_in[2];
    const float* w2b  = (const float*)d_in[3];
    const float* w3a  = (const float*)d_in[4];
    const float* w3b  = (const float*)d_in[5];
    const float* w3c  = (const float*)d_in[6];
    const float* g1   = (const float*)d_in[7];
    const float* g2a  = (const float*)d_in[8];
    const float* g2b  = (const float*)d_in[9];
    const float* g3a  = (const float*)d_in[10];
    const float* g3b  = (const float*)d_in[11];
    const float* g3c  = (const float*)d_in[12];
    const float* b1   = (const float*)d_in[13];
    const float* b2a  = (const float*)d_in[14];
    const float* b2b  = (const float*)d_in[15];
    const float* b3a  = (const float*)d_in[16];
    const float* b3b  = (const float*)d_in[17];
    const float* b3c  = (const float*)d_in[18];
    const float* Wmp  = (const float*)d_in[19];
    const float* bmp  = (const float*)d_in[20];
    const float* Wq   = (const float*)d_in[21];
    const float* Wk   = (const float*)d_in[22];
    const float* Wv   = (const float*)d_in[23];
    const float* Wout = (const float*)d_in[24];
    const float* bout = (const float*)d_in[25];
    float* ws = (float*)d_ws;
    float* out = (float*)d_out;
    u16* wu = (u16*)d_ws;

    prepk<<<3850, 256, 0, stream>>>(x, w1, w2a, w2b, w3a, w3b, w3c,
                                    g1, g2a, g2b, g3a, g3b, g3c,
                                    b1, b2a, b3a, Wmp, Wq, Wk, Wv, Wout, ws);
    megak<<<256, 512, 0, stream>>>(x, b2b, b3b, b3c, bmp, ws);
    attnk<<<dim3(32, 16), 512, 0, stream>>>(ws);
    {   // final: XOb @ WBOUT + bout + MP -> out
        GemmChunks c{};
        c.soff[0]=SXOB;    c.stride[0]=112; c.cols[0]=96;
        c.soff[1]=SXOB+96; c.stride[1]=112; c.cols[1]=16;
        gemmk<2><<<dim3(128,2), 256, 0, stream>>>(c, wu, wu+SBOUT,
            bout, ws+OFF_MP, out, 88, 88);
    }
}